// Round 4
// baseline (1174.848 us; speedup 1.0000x reference)
//
#include <hip/hip_runtime.h>
#include <hip/hip_bf16.h>

// Problem constants
#define NB 64      // batch
#define NS 196     // image tokens
#define NH 512     // hidden
#define NV 10000   // vocab
#define NL 32      // max length
#define NT 31      // T = L-1
#define NSP 197    // S+1
#define LSTM_BLOCKS 32

typedef __attribute__((ext_vector_type(4))) float  f32x4;
typedef __attribute__((ext_vector_type(8))) short  short8;
typedef __attribute__((ext_vector_type(4))) short  s16x4;
typedef __attribute__((ext_vector_type(8))) __bf16 bf16x8;

__device__ __forceinline__ float sigm(float x){ return 1.0f/(1.0f+__expf(-x)); }
__device__ __forceinline__ float tanh_f(float x){ return 1.0f - 2.0f/(1.0f+__expf(2.0f*x)); }
__device__ __forceinline__ short f2bf(float f){
  unsigned u = __float_as_uint(f);
  u += 0x7FFFu + ((u>>16)&1u);           // RNE
  return (short)(u>>16);
}
__device__ __forceinline__ float bf2f(short s){
  return __uint_as_float(((unsigned)(unsigned short)s)<<16);
}

// ---------------------------------------------------------------------------
// Generic transpose+convert: W (K x N, f32, row-major) -> Wt (N x K, bf16)
// ---------------------------------------------------------------------------
__global__ __launch_bounds__(256)
void k_tr_bf(const float* __restrict__ W, short* __restrict__ Wt, int K, int N)
{
  __shared__ float tsh[32][33];
  const int n0 = blockIdx.x*32, k0 = blockIdx.y*32;
  for (int i = threadIdx.x; i < 1024; i += 256) {
    const int kl = i>>5, nl = i&31;
    if (k0+kl < K && n0+nl < N) tsh[kl][nl] = W[(size_t)(k0+kl)*N + n0+nl];
  }
  __syncthreads();
  for (int i = threadIdx.x; i < 1024; i += 256) {
    const int nl = i>>5, kl = i&31;
    if (n0+nl < N && k0+kl < K) Wt[(size_t)(n0+nl)*K + k0+kl] = f2bf(tsh[kl][nl]);
  }
}

// ---------------------------------------------------------------------------
// bf16-MFMA GEMM with pre-transposed B: C = act(A @ B + bias [+ bias2])
// A: M x K row-major (f32 if ABF=0, bf16 if ABF=1), lda in elements.
// Bt: N x K row-major bf16 (i.e. B transposed), ldb in elements.
// Tile 128x128x32, 4 waves. Staging = linear short8 copies for both operands.
// ACT: 0 none, 1 tanh.  CBF: 0 -> f32 C, 1 -> bf16 C.
// ---------------------------------------------------------------------------
template<int ACT, int CBF, int ABF>
__global__ __launch_bounds__(256)
void mfma_gemm2(const void* __restrict__ Ap, int lda,
                const short* __restrict__ Bt, int ldb,
                const float* __restrict__ bias, const float* __restrict__ bias2,
                void* __restrict__ Cp, int ldc,
                int M, int N, int K)
{
  __shared__ short ash[128][40];   // [m][k], pad 40 (80B stride -> conflict-free frag reads)
  __shared__ short bsh[128][40];   // [n][k]
  const int bn0 = blockIdx.x*128, bm0 = blockIdx.y*128;
  const int tid = threadIdx.x;
  const int w = tid>>6, l = tid&63;
  const int wr = w>>1, wc = w&1;
  const int lrow = l&15, lk = (l>>4)*8;

  f32x4 acc[4][4];
  #pragma unroll
  for (int i=0;i<4;++i)
    #pragma unroll
    for (int j=0;j<4;++j){ f32x4 z = {0.f,0.f,0.f,0.f}; acc[i][j] = z; }

  const int srow = tid>>1, skc = (tid&1)*16;   // each thread: one row, 16 k-elems

  const int ksteps = (K+31)>>5;
  for (int ks=0; ks<ksteps; ++ks) {
    const int k0 = ks<<5;
    // ---- stage A (128 x 32) ----
    {
      short8 t0 = {0,0,0,0,0,0,0,0}, t1 = {0,0,0,0,0,0,0,0};
      const int gm = bm0 + srow;
      if (ABF) {
        const short* A = (const short*)Ap;
        if (gm < M) {
          if (k0+skc+16 <= K) {
            const short* src = A + (size_t)gm*lda + (k0+skc);
            t0 = *reinterpret_cast<const short8*>(src);
            t1 = *reinterpret_cast<const short8*>(src+8);
          } else {
            #pragma unroll
            for (int e=0;e<8;++e){ int gk=k0+skc+e;   if (gk<K) t0[e]=A[(size_t)gm*lda+gk]; }
            #pragma unroll
            for (int e=0;e<8;++e){ int gk=k0+skc+8+e; if (gk<K) t1[e]=A[(size_t)gm*lda+gk]; }
          }
        }
      } else {
        const float* A = (const float*)Ap;
        if (gm < M) {
          if (k0+skc+16 <= K) {
            const float* src = A + (size_t)gm*lda + (k0+skc);
            f32x4 v0 = *reinterpret_cast<const f32x4*>(src);
            f32x4 v1 = *reinterpret_cast<const f32x4*>(src+4);
            f32x4 v2 = *reinterpret_cast<const f32x4*>(src+8);
            f32x4 v3 = *reinterpret_cast<const f32x4*>(src+12);
            t0[0]=f2bf(v0.x); t0[1]=f2bf(v0.y); t0[2]=f2bf(v0.z); t0[3]=f2bf(v0.w);
            t0[4]=f2bf(v1.x); t0[5]=f2bf(v1.y); t0[6]=f2bf(v1.z); t0[7]=f2bf(v1.w);
            t1[0]=f2bf(v2.x); t1[1]=f2bf(v2.y); t1[2]=f2bf(v2.z); t1[3]=f2bf(v2.w);
            t1[4]=f2bf(v3.x); t1[5]=f2bf(v3.y); t1[6]=f2bf(v3.z); t1[7]=f2bf(v3.w);
          } else {
            #pragma unroll
            for (int e=0;e<8;++e){ int gk=k0+skc+e;   if (gk<K) t0[e]=f2bf(A[(size_t)gm*lda+gk]); }
            #pragma unroll
            for (int e=0;e<8;++e){ int gk=k0+skc+8+e; if (gk<K) t1[e]=f2bf(A[(size_t)gm*lda+gk]); }
          }
        }
      }
      *reinterpret_cast<short8*>(&ash[srow][skc])   = t0;
      *reinterpret_cast<short8*>(&ash[srow][skc+8]) = t1;
    }
    // ---- stage B (128 x 32) from pre-transposed bf16 ----
    {
      short8 t0 = {0,0,0,0,0,0,0,0}, t1 = {0,0,0,0,0,0,0,0};
      const int gn = bn0 + srow;
      if (gn < N) {
        if (k0+skc+16 <= K) {
          const short* src = Bt + (size_t)gn*ldb + (k0+skc);
          t0 = *reinterpret_cast<const short8*>(src);
          t1 = *reinterpret_cast<const short8*>(src+8);
        } else {
          #pragma unroll
          for (int e=0;e<8;++e){ int gk=k0+skc+e;   if (gk<K) t0[e]=Bt[(size_t)gn*ldb+gk]; }
          #pragma unroll
          for (int e=0;e<8;++e){ int gk=k0+skc+8+e; if (gk<K) t1[e]=Bt[(size_t)gn*ldb+gk]; }
        }
      }
      *reinterpret_cast<short8*>(&bsh[srow][skc])   = t0;
      *reinterpret_cast<short8*>(&bsh[srow][skc+8]) = t1;
    }
    __syncthreads();
    short8 af[4], bfm[4];
    #pragma unroll
    for (int fm=0;fm<4;++fm) af[fm]  = *reinterpret_cast<const short8*>(&ash[wr*64+fm*16+lrow][lk]);
    #pragma unroll
    for (int fn=0;fn<4;++fn) bfm[fn] = *reinterpret_cast<const short8*>(&bsh[wc*64+fn*16+lrow][lk]);
    #pragma unroll
    for (int fm=0;fm<4;++fm)
      #pragma unroll
      for (int fn=0;fn<4;++fn)
        acc[fm][fn] = __builtin_amdgcn_mfma_f32_16x16x32_bf16(
            __builtin_bit_cast(bf16x8, af[fm]),
            __builtin_bit_cast(bf16x8, bfm[fn]),
            acc[fm][fn], 0, 0, 0);
    __syncthreads();
  }
  // ---- epilogue ----
  #pragma unroll
  for (int fm=0;fm<4;++fm){
    #pragma unroll
    for (int fn=0;fn<4;++fn){
      const int gcol = bn0 + wc*64 + fn*16 + lrow;
      if (gcol >= N) continue;
      float bv = 0.f;
      if (bias)  bv += bias[gcol];
      if (bias2) bv += bias2[gcol];
      const int grow0 = bm0 + wr*64 + fm*16 + (l>>4)*4;
      #pragma unroll
      for (int ri=0;ri<4;++ri){
        const int grow = grow0 + ri;
        if (grow >= M) continue;
        float v = acc[fm][fn][ri] + bv;
        if (ACT==1) v = tanh_f(v);
        if (CBF) reinterpret_cast<short*>(Cp)[(size_t)grow*ldc+gcol] = f2bf(v);
        else     reinterpret_cast<float*>(Cp)[(size_t)grow*ldc+gcol] = v;
      }
    }
  }
}

// ---------------------------------------------------------------------------
// img_mean + static_x assembly.  grid (2, NB) x 256
// ---------------------------------------------------------------------------
__global__ __launch_bounds__(256)
void k_mean_static(const float* __restrict__ image, const float* __restrict__ vp,
                   const float* __restrict__ lab, const float* __restrict__ topic,
                   float* __restrict__ imean, float* __restrict__ statx)
{
  const int b = blockIdx.y;
  const int h = blockIdx.x*256 + threadIdx.x;       // 0..511
  float s = 0.f;
  for (int j = 0; j < NS; ++j) s += image[((size_t)b*NS + j)*NH + h];
  const float mn = s * (1.0f/196.0f);
  imean[b*NH + h]       = mn;
  statx[b*1048 + h]     = mn;
  statx[b*1048 + 536+h] = topic[b*NH + h];
  if (blockIdx.x == 0) {
    if (threadIdx.x < 8)       statx[b*1048 + 512 + threadIdx.x]     = vp[b*8 + threadIdx.x];
    else if (threadIdx.x < 24) statx[b*1048 + 520 + (threadIdx.x-8)] = lab[b*16 + threadIdx.x-8];
  }
}

// ---------------------------------------------------------------------------
// embedding gather -> bf16 (time-major rows r = t*64 + b)
// ---------------------------------------------------------------------------
__global__ __launch_bounds__(256)
void k_gather(const float* __restrict__ embW, const int* __restrict__ text,
              short* __restrict__ X)
{
  const int r = blockIdx.x;
  const int t = r >> 6, b = r & 63;
  const int tok = text[b*NL + t];
  for (int e = threadIdx.x; e < NH; e += 256)
    X[(size_t)r*NH + e] = f2bf(embW[(size_t)tok*NH + e]);
}

// f32 -> bf16 bulk convert (n multiple of 1024)
__global__ __launch_bounds__(256)
void k_f2bf_vec(const float* __restrict__ s, short* __restrict__ d, int n)
{
  int i = (blockIdx.x*256 + threadIdx.x)*4;
  if (i+4 <= n) {
    f32x4 v = *reinterpret_cast<const f32x4*>(s+i);
    s16x4 o; o[0]=f2bf(v.x); o[1]=f2bf(v.y); o[2]=f2bf(v.z); o[3]=f2bf(v.w);
    *reinterpret_cast<s16x4*>(d+i) = o;
  }
}

__global__ void k_init_ctr(unsigned* c){ if (threadIdx.x==0 && blockIdx.x==0) *c = 0u; }

// ---------------------------------------------------------------------------
// Persistent LSTM recurrence. 32 blocks x 256 thr. 64KB static LDS (h-buffer;
// the gate-exchange buffer gshm ALIASES its first 17KB, made safe by a
// syncthreads between the last MFMA read of h and the first gshm write).
// Block bx owns 16 gate-columns [bx*16,bx*16+16) of each of the 4 gates;
// wave w = gate w. W_hh^T bf16 fragments live in REGISTERS for all 31 steps
// (weight-stationary, 64 VGPR/lane). Per step: stage h_t (bf16, XOR-swizzled
// source, linear LDS dest) -> MFMA (4 m-frags x 16 k-steps) -> gates via LDS
// -> cell update (m in registers) -> write h_{t+1} f32 (archive) + bf16
// (double-buffered) -> device-scope atomic spin barrier (release add /
// agent-acquire load, bounded spin, monotonic target).
// ---------------------------------------------------------------------------
__global__ __launch_bounds__(256, 1)
void lstm_persist(const float* __restrict__ Gs,   // [64][2048] static x@W_ih + b_ih + b_hh
                  const float* __restrict__ Ge,   // [31][64][2048] emb part
                  const short* __restrict__ WhhT, // [2048][512] bf16
                  short* __restrict__ hbf0,       // [64][512] bf16 (h_t, t even)
                  short* __restrict__ hbf1,       // [64][512] bf16 (t odd)
                  const float* __restrict__ m0,   // [64][512]
                  float* __restrict__ Hout,       // [31][64][512] h_{t+1}, time-major
                  unsigned* __restrict__ ctr)
{
  __shared__ __align__(16) char smem[65536];       // h_t bf16 [64][512] (swizzled)
  float (*gshm)[64][17] = reinterpret_cast<float(*)[64][17]>(smem); // aliases smem
  const int bx = blockIdx.x;
  const int tid = threadIdx.x, w = tid>>6, l = tid&63;
  const int lrow = l&15, lhi = l>>4;
  const int jbase = bx*16;
  const int sw = (lrow&7)<<4;                     // per-lane read swizzle (bytes)

  // W_hh^T fragments, resident in 64 VGPRs for the whole kernel
  short8 bfrag[16];
  {
    const short* wp = WhhT + (size_t)(w*512 + jbase + lrow)*512 + lhi*8;
    #pragma unroll
    for (int ks=0; ks<16; ++ks)
      bfrag[ks] = *reinterpret_cast<const short8*>(wp + ks*32);
  }
  // static gate part (t-invariant): Gs[b][w*512+jbase+lrow], b per (fm,ri)
  float gsr[16];
  #pragma unroll
  for (int fm=0; fm<4; ++fm)
    #pragma unroll
    for (int ri=0; ri<4; ++ri)
      gsr[fm*4+ri] = Gs[(size_t)(fm*16 + lhi*4 + ri)*2048 + w*512 + jbase + lrow];

  // cell-state registers: thread owns (cb, jbase+cj .. +4)
  const int cb = tid>>2, cj = (tid&3)*4;
  float mreg[4];
  #pragma unroll
  for (int q=0; q<4; ++q) mreg[q] = m0[(size_t)cb*512 + jbase + cj + q];

  for (int t=0; t<NT; ++t) {
    // ---- stage h_t: LDS[B] = hbf[(B&~1023) | ((B&1023)^((row&7)<<4))] ----
    {
      const char* hbytes = (const char*)((t&1) ? hbf1 : hbf0);
      #pragma unroll
      for (int q=0; q<16; ++q) {                   // 16*256*16B = 64KB (all 64 rows)
        const int B = (q*256 + tid)*16;
        const int r = B >> 10;
        const int src = (r<<10) | ((B & 1023) ^ ((r&7)<<4));
        *reinterpret_cast<short8*>(smem + B) =
            *reinterpret_cast<const short8*>(hbytes + src);
      }
    }
    // prefetch this step's embedding gate part
    float ger[16];
    {
      const float* ge = Ge + (size_t)t*NB*2048;
      #pragma unroll
      for (int fm=0; fm<4; ++fm)
        #pragma unroll
        for (int ri=0; ri<4; ++ri)
          ger[fm*4+ri] = ge[(size_t)(fm*16 + lhi*4 + ri)*2048 + w*512 + jbase + lrow];
    }
    __syncthreads();

    // ---- h_t @ W_hh (gate w, 16 cols): 4 m-frags x 16 k-steps ----
    f32x4 acc[4];
    #pragma unroll
    for (int fm=0; fm<4; ++fm){ f32x4 z = {0.f,0.f,0.f,0.f}; acc[fm] = z; }
    #pragma unroll
    for (int ks=0; ks<16; ++ks) {
      const int kb = ks*64 + lhi*16;               // byte offset of lane's k-slice
      #pragma unroll
      for (int fm=0; fm<4; ++fm) {
        const int r = fm*16 + lrow;
        const short8 a = *reinterpret_cast<const short8*>(smem + r*1024 + (kb ^ sw));
        acc[fm] = __builtin_amdgcn_mfma_f32_16x16x32_bf16(
            __builtin_bit_cast(bf16x8, a),
            __builtin_bit_cast(bf16x8, bfrag[ks]), acc[fm], 0, 0, 0);
      }
    }
    __syncthreads();   // all h reads done before gshm (aliased) is written

    // gates -> LDS (MFMA C layout: col=lane&15, row=(lane>>4)*4+reg)
    #pragma unroll
    for (int fm=0; fm<4; ++fm)
      #pragma unroll
      for (int ri=0; ri<4; ++ri)
        gshm[w][fm*16 + lhi*4 + ri][lrow] = acc[fm][ri] + gsr[fm*4+ri] + ger[fm*4+ri];
    __syncthreads();

    // ---- cell update (4 elements/thread, m in registers) ----
    float h2v[4];
    #pragma unroll
    for (int q=0; q<4; ++q) {
      const float gi = gshm[0][cb][cj+q];
      const float gf = gshm[1][cb][cj+q];
      const float gg = gshm[2][cb][cj+q];
      const float go = gshm[3][cb][cj+q];
      mreg[q] = sigm(gf)*mreg[q] + sigm(gi)*tanh_f(gg);
      h2v[q]  = sigm(go)*tanh_f(mreg[q]);
    }
    {
      float* ho = Hout + ((size_t)t*NB + cb)*NH + jbase + cj;
      ho[0]=h2v[0]; ho[1]=h2v[1]; ho[2]=h2v[2]; ho[3]=h2v[3];
      short* hn = ((t&1) ? hbf0 : hbf1) + (size_t)cb*512 + jbase + cj;
      hn[0]=f2bf(h2v[0]); hn[1]=f2bf(h2v[1]); hn[2]=f2bf(h2v[2]); hn[3]=f2bf(h2v[3]);
    }

    // ---- grid barrier (skip after last step) ----
    if (t != NT-1) {
      __threadfence();
      __syncthreads();
      if (tid == 0) {
        __hip_atomic_fetch_add(ctr, 1u, __ATOMIC_RELEASE, __HIP_MEMORY_SCOPE_AGENT);
        const unsigned tgt = (unsigned)LSTM_BLOCKS * (unsigned)(t+1);
        unsigned spins = 0;
        while (__hip_atomic_load(ctr, __ATOMIC_ACQUIRE, __HIP_MEMORY_SCOPE_AGENT) < tgt
               && ++spins < (1u<<22)) { }
      }
      __syncthreads();
    }
  }
}

// ---------------------------------------------------------------------------
// zz[.,196] = dot(tanh(_s+_h), zW)   (one wave per row)
// ---------------------------------------------------------------------------
__global__ __launch_bounds__(256)
void k_zs(const float* __restrict__ Hh, const float* __restrict__ Ss,
          const float* __restrict__ zw, float* __restrict__ zz)
{
  const int wid = blockIdx.x*4 + (threadIdx.x >> 6);   // row (time-major)
  const int l = threadIdx.x & 63;
  const int t = wid >> 6, b = wid & 63;
  float s = 0.f;
  #pragma unroll
  for (int j = 0; j < 8; ++j) {
    const int h = l + 64*j;
    s += tanh_f(Hh[(size_t)wid*NH + h] + Ss[(size_t)wid*NH + h]) * zw[h];
  }
  #pragma unroll
  for (int off = 1; off < 64; off <<= 1) s += __shfl_xor(s, off);
  if (l == 0) zz[((size_t)b*NT + t)*200 + 196] = s;
}

// ---------------------------------------------------------------------------
// zz[b,t,s] = sum_h tanh(v_proj[b,s,h] + _h[b,t,h]) * zW[h]
// block = (s-tile of 16) x one b; v_proj(bf16) read exactly once.
// ---------------------------------------------------------------------------
__global__ __launch_bounds__(256)
void k_att1(const short* __restrict__ vpbf, const float* __restrict__ Hh,
            const float* __restrict__ zw, float* __restrict__ zz)
{
  __shared__ short vp_sh[16][512];
  __shared__ short hh_sh[NT][512];
  __shared__ float zw_sh[512];
  const int b = blockIdx.y, s0 = blockIdx.x*16;
  for (int i = threadIdx.x; i < 1024; i += 256) {        // short8 units
    const int row = i >> 6, c8 = (i & 63)*8;
    const int gs = s0 + row;
    short8 v = {0,0,0,0,0,0,0,0};
    if (gs < NS) v = *reinterpret_cast<const short8*>(&vpbf[((size_t)b*NS + gs)*NH + c8]);
    *reinterpret_cast<short8*>(&vp_sh[row][c8]) = v;
  }
  for (int i = threadIdx.x; i < NT*512; i += 256) {
    const int t = i >> 9, h = i & 511;
    hh_sh[t][h] = f2bf(Hh[((size_t)t*NB + b)*NH + h]);
  }
  for (int i = threadIdx.x; i < 512; i += 256) zw_sh[i] = zw[i];
  __syncthreads();
  const int w = threadIdx.x >> 6, l = threadIdx.x & 63;
  for (int si = w; si < 16; si += 4) {
    const int gs = s0 + si;
    if (gs >= NS) continue;
    float vv[8], zv[8];
    #pragma unroll
    for (int j = 0; j < 8; ++j) {
      const int h = l + 64*j;
      vv[j] = bf2f(vp_sh[si][h]);
      zv[j] = zw_sh[h];
    }
    for (int t = 0; t < NT; ++t) {
      float acc = 0.f;
      #pragma unroll
      for (int j = 0; j < 8; ++j) {
        const int h = l + 64*j;
        acc += tanh_f(vv[j] + bf2f(hh_sh[t][h])) * zv[j];
      }
      #pragma unroll
      for (int off = 1; off < 64; off <<= 1) acc += __shfl_xor(acc, off);
      if (l == 0) zz[((size_t)b*NT + t)*200 + gs] = acc;
    }
  }
}

// ---------------------------------------------------------------------------
// softmax over 197 per row; write masked att to d_out and raw a to ws
// ---------------------------------------------------------------------------
__global__ __launch_bounds__(256)
void k_att2(const float* __restrict__ zz, const int* __restrict__ length,
            float* __restrict__ att, float* __restrict__ abuf)
{
  __shared__ float red[4];
  const int rowm = blockIdx.x;
  const int b = rowm / NT, t = rowm % NT;
  const int tid = threadIdx.x, w = tid >> 6, l = tid & 63;
  float v = -1e30f;
  if (tid < NSP) v = zz[(size_t)rowm*200 + tid];
  float mx = v;
  #pragma unroll
  for (int off = 1; off < 64; off <<= 1) mx = fmaxf(mx, __shfl_xor(mx, off));
  if (l == 0) red[w] = mx;
  __syncthreads();
  mx = fmaxf(fmaxf(red[0], red[1]), fmaxf(red[2], red[3]));
  __syncthreads();
  float p = (tid < NSP) ? __expf(v - mx) : 0.f;
  float sm = p;
  #pragma unroll
  for (int off = 1; off < 64; off <<= 1) sm += __shfl_xor(sm, off);
  if (l == 0) red[w] = sm;
  __syncthreads();
  const float sum = red[0] + red[1] + red[2] + red[3];
  if (tid < NSP) {
    const float a = p / sum;
    abuf[(size_t)rowm*NSP + tid] = a;
    const int msk = (t < length[b] - 1);
    att[(size_t)rowm*NSP + tid] = msk ? a : 0.f;
  }
}

// ---------------------------------------------------------------------------
// c = a[:,:S] @ image + a[:,S]*s ; R = bf16(c + h2)  (per-b, image read ~once)
// ---------------------------------------------------------------------------
__global__ __launch_bounds__(256)
void k_att3(const float* __restrict__ abuf, const float* __restrict__ image,
            const float* __restrict__ HS, const float* __restrict__ H2,
            short* __restrict__ R)
{
  __shared__ float a_sh[NT][NSP];
  const int b = blockIdx.y;
  const int h = blockIdx.x*256 + threadIdx.x;
  for (int i = threadIdx.x; i < NT*NSP; i += 256)
    a_sh[i/NSP][i%NSP] = abuf[((size_t)b*NT + i/NSP)*NSP + (i%NSP)];
  __syncthreads();
  float acc[NT];
  #pragma unroll
  for (int t = 0; t < NT; ++t) acc[t] = 0.f;
  for (int s = 0; s < NS; ++s) {
    const float x = image[((size_t)b*NS + s)*NH + h];
    #pragma unroll
    for (int t = 0; t < NT; ++t) acc[t] = fmaf(a_sh[t][s], x, acc[t]);
  }
  #pragma unroll
  for (int t = 0; t < NT; ++t) {
    const size_t r = (size_t)t*NB + b;            // time-major row
    const float sv  = HS[r*1024 + 512 + h];
    const float h2v = H2[r*NH + h];
    R[((size_t)b*NT + t)*NH + h] = f2bf(acc[t] + a_sh[t][196]*sv + h2v);
  }
}

// ---------------------------------------------------------------------------
// in-place log_softmax(logits)/temp with masking, per row of 10000
// ---------------------------------------------------------------------------
__global__ __launch_bounds__(256)
void k_logsm(float* __restrict__ logp, const int* __restrict__ length,
             const float* __restrict__ temp)
{
  __shared__ float red[4];
  const int row = blockIdx.x;
  const int b = row / NT, t = row % NT;
  float* p = logp + (size_t)row*NV;
  f32x4* p4 = reinterpret_cast<f32x4*>(p);
  const int tid = threadIdx.x, w = tid >> 6, l = tid & 63;
  const bool masked = !(t < length[b] - 1);
  if (masked) {
    f32x4 z = {0.f,0.f,0.f,0.f};
    for (int i = tid; i < NV/4; i += 256) p4[i] = z;
    return;
  }
  float mx = -1e30f;
  for (int i = tid; i < NV/4; i += 256) {
    f32x4 v = p4[i];
    mx = fmaxf(mx, fmaxf(fmaxf(v.x, v.y), fmaxf(v.z, v.w)));
  }
  #pragma unroll
  for (int off = 1; off < 64; off <<= 1) mx = fmaxf(mx, __shfl_xor(mx, off));
  if (l == 0) red[w] = mx;
  __syncthreads();
  mx = fmaxf(fmaxf(red[0], red[1]), fmaxf(red[2], red[3]));
  __syncthreads();
  float sm = 0.f;
  for (int i = tid; i < NV/4; i += 256) {
    f32x4 v = p4[i];
    sm += __expf(v.x - mx) + __expf(v.y - mx) + __expf(v.z - mx) + __expf(v.w - mx);
  }
  #pragma unroll
  for (int off = 1; off < 64; off <<= 1) sm += __shfl_xor(sm, off);
  if (l == 0) red[w] = sm;
  __syncthreads();
  const float lse = __logf(red[0] + red[1] + red[2] + red[3]);
  const float rt = 1.0f / temp[b];
  const float sh = mx + lse;
  for (int i = tid; i < NV/4; i += 256) {
    f32x4 v = p4[i];
    v.x = (v.x - sh)*rt; v.y = (v.y - sh)*rt; v.z = (v.z - sh)*rt; v.w = (v.w - sh)*rt;
    p4[i] = v;
  }
}

// ---------------------------------------------------------------------------
// workspace layout (float units; bf16 buffers count elements/2)
// ---------------------------------------------------------------------------
static const size_t O_STATIC = 0;                              // 64*1048 f32
static const size_t O_IMEAN  = O_STATIC + (size_t)64*1048;
static const size_t O_H0     = O_IMEAN  + (size_t)64*512;
static const size_t O_M      = O_H0     + (size_t)64*512;      // m0 (read-only)
static const size_t O_GSTAT  = O_M      + (size_t)64*512;      // 64*2048 f32
static const size_t O_XEMB   = O_GSTAT  + (size_t)64*2048;     // 1984*512 bf16
static const size_t O_GEMB   = O_XEMB   + (size_t)1984*256;    // 1984*2048 f32
static const size_t O_H2     = O_GEMB   + (size_t)1984*2048;   // 1984*512 f32
static const size_t O_HS     = O_H2     + (size_t)1984*512;    // 1984*1024 f32
static const size_t O_HH     = O_HS     + (size_t)1984*1024;   // 1984*512 f32
static const size_t O_SS     = O_HH     + (size_t)1984*512;    // 1984*512 f32
static const size_t O_R      = O_SS     + (size_t)1984*512;    // 1984*512 bf16
static const size_t O_ZZ     = O_R      + (size_t)1984*256;    // 1984*200 f32
static const size_t O_ABUF   = O_ZZ     + (size_t)1984*200;    // 1984*197 f32
static const size_t O_VPBF   = O_ABUF   + (size_t)1984*197;    // 12544*512 bf16
static const size_t O_WHHT   = O_VPBF   + (size_t)12544*256;   // 2048*512 bf16
static const size_t O_HBF0   = O_WHHT   + (size_t)2048*256;    // 64*512 bf16
static const size_t O_HBF1   = O_HBF0   + (size_t)64*256;
static const size_t O_CTR    = O_HBF1   + (size_t)64*256;      // barrier counter
static const size_t O_WTFCH  = O_CTR    + 64;                  // 512*512 bf16
static const size_t O_WTFCM  = O_WTFCH  + (size_t)512*256;
static const size_t O_WTIHS  = O_WTFCM  + (size_t)512*256;     // 2048*1048 bf16
static const size_t O_WTIHE  = O_WTIHS  + (size_t)2048*524;    // 2048*512 bf16
static const size_t O_WTAV   = O_WTIHE  + (size_t)2048*256;    // 512*512 bf16
static const size_t O_WTAFC  = O_WTAV   + (size_t)512*256;     // 1024*512 bf16
static const size_t O_WTAHH  = O_WTAFC  + (size_t)1024*256;    // 512*512 bf16
static const size_t O_WTASS  = O_WTAHH  + (size_t)512*256;     // 512*512 bf16
static const size_t O_WTFCP  = O_WTASS  + (size_t)512*256;     // 10000*512 bf16
static const size_t OFF_LOGP = (size_t)NB*NT*NSP;              // in d_out floats

extern "C" void kernel_launch(void* const* d_in, const int* in_sizes, int n_in,
                              void* d_out, int out_size, void* d_ws, size_t ws_size,
                              hipStream_t stream) {
  const float* image   = (const float*)d_in[0];
  const float* viewp   = (const float*)d_in[1];
  const float* label   = (const float*)d_in[2];
  const float* topic   = (const float*)d_in[3];
  const float* temp    = (const float*)d_in[4];
  const float* embW    = (const float*)d_in[5];
  const float* fc_h_W  = (const float*)d_in[6];
  const float* fc_h_b  = (const float*)d_in[7];
  const float* fc_m_W  = (const float*)d_in[8];
  const float* fc_m_b  = (const float*)d_in[9];
  const float* W_ih    = (const float*)d_in[10];
  const float* W_hh    = (const float*)d_in[11];
  const float* b_ih    = (const float*)d_in[12];
  const float* b_hh    = (const float*)d_in[13];
  const float* att_fc_W= (const float*)d_in[14];
  const float* att_fc_b= (const float*)d_in[15];
  const float* att_v_W = (const float*)d_in[16];
  const float* att_v_b = (const float*)d_in[17];
  const float* att_hh_W= (const float*)d_in[18];
  const float* att_hh_b= (const float*)d_in[19];
  const float* att_s_W = (const float*)d_in[20];
  const float* att_s_b = (const float*)d_in[21];
  const float* att_z_W = (const float*)d_in[22];
  // d_in[23] att_z_b: constant shift under softmax -> drops out
  const float* fc_p_W  = (const float*)d_in[24];
  const float* fc_p_b  = (const float*)d_in[25];
  const int*   text    = (const int*)d_in[26];
  const int*   length  = (const int*)d_in[27];

  float* ws = (float*)d_ws;
  float* out_att  = (float*)d_out;
  float* out_logp = (float*)d_out + OFF_LOGP;
  short* xemb  = (short*)(ws + O_XEMB);
  short* rbf   = (short*)(ws + O_R);
  short* vpbf  = (short*)(ws + O_VPBF);
  short* whhT  = (short*)(ws + O_WHHT);
  short* hbf0  = (short*)(ws + O_HBF0);
  short* hbf1  = (short*)(ws + O_HBF1);
  unsigned* ctr = (unsigned*)(ws + O_CTR);
  short* wtfch = (short*)(ws + O_WTFCH);
  short* wtfcm = (short*)(ws + O_WTFCM);
  short* wtihs = (short*)(ws + O_WTIHS);
  short* wtihe = (short*)(ws + O_WTIHE);
  short* wtav  = (short*)(ws + O_WTAV);
  short* wtafc = (short*)(ws + O_WTAFC);
  short* wtahh = (short*)(ws + O_WTAHH);
  short* wtass = (short*)(ws + O_WTASS);
  short* wtfcp = (short*)(ws + O_WTFCP);

  // phase 0a: weight transposes (f32 KxN -> bf16 NxK), means, gathers
  k_init_ctr<<<1, 64, 0, stream>>>(ctr);
  k_mean_static<<<dim3(2,NB), 256, 0, stream>>>(image, viewp, label, topic,
                                                ws+O_IMEAN, ws+O_STATIC);
  k_gather<<<NB*NT, 256, 0, stream>>>(embW, text, xemb);
  k_tr_bf<<<dim3(16,16),  256, 0, stream>>>(fc_h_W,  wtfch, 512, 512);
  k_tr_bf<<<dim3(16,16),  256, 0, stream>>>(fc_m_W,  wtfcm, 512, 512);
  k_tr_bf<<<dim3(64,33),  256, 0, stream>>>(W_ih,    wtihs, 1048, 2048);
  k_tr_bf<<<dim3(64,16),  256, 0, stream>>>(W_ih + (size_t)1048*2048, wtihe, 512, 2048);
  k_tr_bf<<<dim3(64,16),  256, 0, stream>>>(W_hh,    whhT,  512, 2048);
  k_tr_bf<<<dim3(16,16),  256, 0, stream>>>(att_v_W, wtav,  512, 512);
  k_tr_bf<<<dim3(32,16),  256, 0, stream>>>(att_fc_W,wtafc, 512, 1024);
  k_tr_bf<<<dim3(16,16),  256, 0, stream>>>(att_hh_W,wtahh, 512, 512);
  k_tr_bf<<<dim3(16,16),  256, 0, stream>>>(att_s_W, wtass, 512, 512);
  k_tr_bf<<<dim3(313,16), 256, 0, stream>>>(fc_p_W,  wtfcp, 512, 10000);

  // phase 0b: one-shot GEMMs
  mfma_gemm2<1,0,0><<<dim3(4,1), 256, 0, stream>>>(ws+O_IMEAN,512, wtfch,512,
      fc_h_b,nullptr, ws+O_H0,512, 64,512,512);
  mfma_gemm2<1,0,0><<<dim3(4,1), 256, 0, stream>>>(ws+O_IMEAN,512, wtfcm,512,
      fc_m_b,nullptr, ws+O_M,512, 64,512,512);
  mfma_gemm2<0,0,0><<<dim3(16,1), 256, 0, stream>>>(ws+O_STATIC,1048, wtihs,1048,
      b_ih,b_hh, ws+O_GSTAT,2048, 64,2048,1048);
  mfma_gemm2<0,0,1><<<dim3(16,16), 256, 0, stream>>>(xemb,512, wtihe,512,
      nullptr,nullptr, ws+O_GEMB,2048, 1984,2048,512);
  mfma_gemm2<0,1,0><<<dim3(4,98), 256, 0, stream>>>(image,512, wtav,512,
      att_v_b,nullptr, vpbf,512, 12544,512,512);
  k_f2bf_vec<<<32, 256, 0, stream>>>(ws+O_H0, hbf0, NB*NH);

  // phase 1: whole recurrence in ONE persistent kernel
  lstm_persist<<<LSTM_BLOCKS, 256, 0, stream>>>(ws+O_GSTAT, ws+O_GEMB, whhT,
                                                hbf0, hbf1, ws+O_M, ws+O_H2, ctr);

  // phase 2: batched attention over all B*T rows
  mfma_gemm2<1,0,0><<<dim3(8,16), 256, 0, stream>>>(ws+O_H2,512, wtafc,512,
      att_fc_b,nullptr, ws+O_HS,1024, 1984,1024,512);
  mfma_gemm2<0,0,0><<<dim3(4,16), 256, 0, stream>>>(ws+O_HS,1024, wtahh,512,
      att_hh_b,nullptr, ws+O_HH,512, 1984,512,512);
  mfma_gemm2<0,0,0><<<dim3(4,16), 256, 0, stream>>>(ws+O_HS+512,1024, wtass,512,
      att_s_b,nullptr, ws+O_SS,512, 1984,512,512);
  k_zs<<<NB*NT/4, 256, 0, stream>>>(ws+O_HH, ws+O_SS, att_z_W, ws+O_ZZ);
  k_att1<<<dim3(13,NB), 256, 0, stream>>>(vpbf, ws+O_HH, att_z_W, ws+O_ZZ);
  k_att2<<<NB*NT, 256, 0, stream>>>(ws+O_ZZ, length, out_att, ws+O_ABUF);
  k_att3<<<dim3(2,NB), 256, 0, stream>>>(ws+O_ABUF, image, ws+O_HS, ws+O_H2, rbf);

  // phase 3: vocab projection + fused log_softmax (logits in-place in d_out)
  mfma_gemm2<0,0,1><<<dim3(79,16), 256, 0, stream>>>(rbf,512, wtfcp,512,
      fc_p_b,nullptr, out_logp,10000, 1984,10000,512);
  k_logsm<<<NB*NT, 256, 0, stream>>>(out_logp, length, temp);
}

// Round 5
// 1047.919 us; speedup vs baseline: 1.1211x; 1.1211x over previous
//
#include <hip/hip_runtime.h>
#include <hip/hip_bf16.h>

// Problem constants
#define NB 64      // batch
#define NS 196     // image tokens
#define NH 512     // hidden
#define NV 10000   // vocab
#define NL 32      // max length
#define NT 31      // T = L-1
#define NSP 197    // S+1
#define LSTM_BLOCKS 32

typedef __attribute__((ext_vector_type(4))) float  f32x4;
typedef __attribute__((ext_vector_type(8))) short  short8;
typedef __attribute__((ext_vector_type(4))) short  s16x4;
typedef __attribute__((ext_vector_type(8))) __bf16 bf16x8;

__device__ __forceinline__ float sigm(float x){ return 1.0f/(1.0f+__expf(-x)); }
__device__ __forceinline__ float tanh_f(float x){ return 1.0f - 2.0f/(1.0f+__expf(2.0f*x)); }
__device__ __forceinline__ short f2bf(float f){
  unsigned u = __float_as_uint(f);
  u += 0x7FFFu + ((u>>16)&1u);           // RNE
  return (short)(u>>16);
}
__device__ __forceinline__ float bf2f(short s){
  return __uint_as_float(((unsigned)(unsigned short)s)<<16);
}

// ---------------------------------------------------------------------------
// Batched transpose+convert: for each job, W (K x N f32) -> Wt (N x K bf16).
// One launch for all weights: saves ~9 serialized graph nodes.
// ---------------------------------------------------------------------------
#define NJOBS 10
struct TrJob { const float* src; short* dst; int K; int N; int tcols; };
struct TrJobs { TrJob j[NJOBS]; int cum[NJOBS+1]; };

__global__ __launch_bounds__(256)
void k_tr_all(TrJobs jobs)
{
  __shared__ float tsh[32][33];
  const int g = blockIdx.x;
  int ji = 0;
  #pragma unroll
  for (int i = 0; i < NJOBS; ++i) if (g >= jobs.cum[i+1]) ji = i+1;
  const TrJob J = jobs.j[ji];
  const int lt = g - jobs.cum[ji];
  const int n0 = (lt % J.tcols)*32, k0 = (lt / J.tcols)*32;
  for (int i = threadIdx.x; i < 1024; i += 256) {
    const int kl = i>>5, nl = i&31;
    if (k0+kl < J.K && n0+nl < J.N) tsh[kl][nl] = J.src[(size_t)(k0+kl)*J.N + n0+nl];
  }
  __syncthreads();
  for (int i = threadIdx.x; i < 1024; i += 256) {
    const int nl = i>>5, kl = i&31;
    if (n0+nl < J.N && k0+kl < J.K) J.dst[(size_t)(n0+nl)*J.K + k0+kl] = f2bf(tsh[kl][nl]);
  }
}

// ---------------------------------------------------------------------------
// bf16-MFMA GEMM with pre-transposed B: C = act(A @ B + bias [+ bias2])
// A: M x K row-major (f32 if ABF=0, bf16 if ABF=1), lda in elements.
// Bt: N x K row-major bf16 (i.e. B transposed), ldb in elements.
// Tile 128x128x32, 4 waves. Staging = linear short8 copies for both operands.
// ACT: 0 none, 1 tanh.  CBF: 0 -> f32 C, 1 -> bf16 C.
// ---------------------------------------------------------------------------
template<int ACT, int CBF, int ABF>
__global__ __launch_bounds__(256)
void mfma_gemm2(const void* __restrict__ Ap, int lda,
                const short* __restrict__ Bt, int ldb,
                const float* __restrict__ bias, const float* __restrict__ bias2,
                void* __restrict__ Cp, int ldc,
                int M, int N, int K)
{
  __shared__ short ash[128][40];   // [m][k], pad 40 (80B stride -> conflict-free frag reads)
  __shared__ short bsh[128][40];   // [n][k]
  const int bn0 = blockIdx.x*128, bm0 = blockIdx.y*128;
  const int tid = threadIdx.x;
  const int w = tid>>6, l = tid&63;
  const int wr = w>>1, wc = w&1;
  const int lrow = l&15, lk = (l>>4)*8;

  f32x4 acc[4][4];
  #pragma unroll
  for (int i=0;i<4;++i)
    #pragma unroll
    for (int j=0;j<4;++j){ f32x4 z = {0.f,0.f,0.f,0.f}; acc[i][j] = z; }

  const int srow = tid>>1, skc = (tid&1)*16;   // each thread: one row, 16 k-elems

  const int ksteps = (K+31)>>5;
  for (int ks=0; ks<ksteps; ++ks) {
    const int k0 = ks<<5;
    // ---- stage A (128 x 32) ----
    {
      short8 t0 = {0,0,0,0,0,0,0,0}, t1 = {0,0,0,0,0,0,0,0};
      const int gm = bm0 + srow;
      if (ABF) {
        const short* A = (const short*)Ap;
        if (gm < M) {
          if (k0+skc+16 <= K) {
            const short* src = A + (size_t)gm*lda + (k0+skc);
            t0 = *reinterpret_cast<const short8*>(src);
            t1 = *reinterpret_cast<const short8*>(src+8);
          } else {
            #pragma unroll
            for (int e=0;e<8;++e){ int gk=k0+skc+e;   if (gk<K) t0[e]=A[(size_t)gm*lda+gk]; }
            #pragma unroll
            for (int e=0;e<8;++e){ int gk=k0+skc+8+e; if (gk<K) t1[e]=A[(size_t)gm*lda+gk]; }
          }
        }
      } else {
        const float* A = (const float*)Ap;
        if (gm < M) {
          if (k0+skc+16 <= K) {
            const float* src = A + (size_t)gm*lda + (k0+skc);
            f32x4 v0 = *reinterpret_cast<const f32x4*>(src);
            f32x4 v1 = *reinterpret_cast<const f32x4*>(src+4);
            f32x4 v2 = *reinterpret_cast<const f32x4*>(src+8);
            f32x4 v3 = *reinterpret_cast<const f32x4*>(src+12);
            t0[0]=f2bf(v0.x); t0[1]=f2bf(v0.y); t0[2]=f2bf(v0.z); t0[3]=f2bf(v0.w);
            t0[4]=f2bf(v1.x); t0[5]=f2bf(v1.y); t0[6]=f2bf(v1.z); t0[7]=f2bf(v1.w);
            t1[0]=f2bf(v2.x); t1[1]=f2bf(v2.y); t1[2]=f2bf(v2.z); t1[3]=f2bf(v2.w);
            t1[4]=f2bf(v3.x); t1[5]=f2bf(v3.y); t1[6]=f2bf(v3.z); t1[7]=f2bf(v3.w);
          } else {
            #pragma unroll
            for (int e=0;e<8;++e){ int gk=k0+skc+e;   if (gk<K) t0[e]=f2bf(A[(size_t)gm*lda+gk]); }
            #pragma unroll
            for (int e=0;e<8;++e){ int gk=k0+skc+8+e; if (gk<K) t1[e]=f2bf(A[(size_t)gm*lda+gk]); }
          }
        }
      }
      *reinterpret_cast<short8*>(&ash[srow][skc])   = t0;
      *reinterpret_cast<short8*>(&ash[srow][skc+8]) = t1;
    }
    // ---- stage B (128 x 32) from pre-transposed bf16 ----
    {
      short8 t0 = {0,0,0,0,0,0,0,0}, t1 = {0,0,0,0,0,0,0,0};
      const int gn = bn0 + srow;
      if (gn < N) {
        if (k0+skc+16 <= K) {
          const short* src = Bt + (size_t)gn*ldb + (k0+skc);
          t0 = *reinterpret_cast<const short8*>(src);
          t1 = *reinterpret_cast<const short8*>(src+8);
        } else {
          #pragma unroll
          for (int e=0;e<8;++e){ int gk=k0+skc+e;   if (gk<K) t0[e]=Bt[(size_t)gn*ldb+gk]; }
          #pragma unroll
          for (int e=0;e<8;++e){ int gk=k0+skc+8+e; if (gk<K) t1[e]=Bt[(size_t)gn*ldb+gk]; }
        }
      }
      *reinterpret_cast<short8*>(&bsh[srow][skc])   = t0;
      *reinterpret_cast<short8*>(&bsh[srow][skc+8]) = t1;
    }
    __syncthreads();
    short8 af[4], bfm[4];
    #pragma unroll
    for (int fm=0;fm<4;++fm) af[fm]  = *reinterpret_cast<const short8*>(&ash[wr*64+fm*16+lrow][lk]);
    #pragma unroll
    for (int fn=0;fn<4;++fn) bfm[fn] = *reinterpret_cast<const short8*>(&bsh[wc*64+fn*16+lrow][lk]);
    #pragma unroll
    for (int fm=0;fm<4;++fm)
      #pragma unroll
      for (int fn=0;fn<4;++fn)
        acc[fm][fn] = __builtin_amdgcn_mfma_f32_16x16x32_bf16(
            __builtin_bit_cast(bf16x8, af[fm]),
            __builtin_bit_cast(bf16x8, bfm[fn]),
            acc[fm][fn], 0, 0, 0);
    __syncthreads();
  }
  // ---- epilogue ----
  #pragma unroll
  for (int fm=0;fm<4;++fm){
    #pragma unroll
    for (int fn=0;fn<4;++fn){
      const int gcol = bn0 + wc*64 + fn*16 + lrow;
      if (gcol >= N) continue;
      float bv = 0.f;
      if (bias)  bv += bias[gcol];
      if (bias2) bv += bias2[gcol];
      const int grow0 = bm0 + wr*64 + fm*16 + (l>>4)*4;
      #pragma unroll
      for (int ri=0;ri<4;++ri){
        const int grow = grow0 + ri;
        if (grow >= M) continue;
        float v = acc[fm][fn][ri] + bv;
        if (ACT==1) v = tanh_f(v);
        if (CBF) reinterpret_cast<short*>(Cp)[(size_t)grow*ldc+gcol] = f2bf(v);
        else     reinterpret_cast<float*>(Cp)[(size_t)grow*ldc+gcol] = v;
      }
    }
  }
}

// ---------------------------------------------------------------------------
// img_mean + static_x assembly.  grid (2, NB) x 256
// ---------------------------------------------------------------------------
__global__ __launch_bounds__(256)
void k_mean_static(const float* __restrict__ image, const float* __restrict__ vp,
                   const float* __restrict__ lab, const float* __restrict__ topic,
                   float* __restrict__ imean, float* __restrict__ statx)
{
  const int b = blockIdx.y;
  const int h = blockIdx.x*256 + threadIdx.x;       // 0..511
  float s = 0.f;
  for (int j = 0; j < NS; ++j) s += image[((size_t)b*NS + j)*NH + h];
  const float mn = s * (1.0f/196.0f);
  imean[b*NH + h]       = mn;
  statx[b*1048 + h]     = mn;
  statx[b*1048 + 536+h] = topic[b*NH + h];
  if (blockIdx.x == 0) {
    if (threadIdx.x < 8)       statx[b*1048 + 512 + threadIdx.x]     = vp[b*8 + threadIdx.x];
    else if (threadIdx.x < 24) statx[b*1048 + 520 + (threadIdx.x-8)] = lab[b*16 + threadIdx.x-8];
  }
}

// ---------------------------------------------------------------------------
// embedding gather -> bf16 (time-major rows r = t*64 + b)
// ---------------------------------------------------------------------------
__global__ __launch_bounds__(256)
void k_gather(const float* __restrict__ embW, const int* __restrict__ text,
              short* __restrict__ X)
{
  const int r = blockIdx.x;
  const int t = r >> 6, b = r & 63;
  const int tok = text[b*NL + t];
  for (int e = threadIdx.x; e < NH; e += 256)
    X[(size_t)r*NH + e] = f2bf(embW[(size_t)tok*NH + e]);
}

// f32 -> bf16 bulk convert (n multiple of 1024)
__global__ __launch_bounds__(256)
void k_f2bf_vec(const float* __restrict__ s, short* __restrict__ d, int n)
{
  int i = (blockIdx.x*256 + threadIdx.x)*4;
  if (i+4 <= n) {
    f32x4 v = *reinterpret_cast<const f32x4*>(s+i);
    s16x4 o; o[0]=f2bf(v.x); o[1]=f2bf(v.y); o[2]=f2bf(v.z); o[3]=f2bf(v.w);
    *reinterpret_cast<s16x4*>(d+i) = o;
  }
}

__global__ void k_init_ctr(unsigned* c){ if (threadIdx.x==0 && blockIdx.x==0) *c = 0u; }

// ---------------------------------------------------------------------------
// Persistent LSTM recurrence. 32 blocks x 256 thr. 64KB static LDS (h-buffer;
// gate-exchange buffer gshm ALIASES it, made safe by a syncthreads between
// the last MFMA read of h and the first gshm write). Block bx owns 16
// gate-columns of each gate; wave w = gate w. W_hh^T bf16 fragments live in
// REGISTERS for all 31 steps. Grid barrier per step:
//   syncthreads (drains vmcnt -> h stores dirty in L2)
//   tid0: fetch_add RELEASE (one L2 writeback) -> spin on RELAXED loads
//         (+s_sleep, no invalidate per poll) -> one ACQUIRE load (one inv)
//   syncthreads
// This replaces r4's acquire-per-poll + threadfence (double flush), which
// profiled at 13.5us/step with 0.4% MfmaUtil.
// ---------------------------------------------------------------------------
__global__ __launch_bounds__(256, 1)
void lstm_persist(const float* __restrict__ Gs,   // [64][2048] static x@W_ih + b_ih + b_hh
                  const float* __restrict__ Ge,   // [31][64][2048] emb part
                  const short* __restrict__ WhhT, // [2048][512] bf16
                  short* __restrict__ hbf0,       // [64][512] bf16 (h_t, t even)
                  short* __restrict__ hbf1,       // [64][512] bf16 (t odd)
                  const float* __restrict__ m0,   // [64][512]
                  float* __restrict__ Hout,       // [31][64][512] h_{t+1}, time-major
                  unsigned* __restrict__ ctr)
{
  __shared__ __align__(16) char smem[65536];       // h_t bf16 [64][512] (swizzled)
  float (*gshm)[64][17] = reinterpret_cast<float(*)[64][17]>(smem); // aliases smem
  const int bx = blockIdx.x;
  const int tid = threadIdx.x, w = tid>>6, l = tid&63;
  const int lrow = l&15, lhi = l>>4;
  const int jbase = bx*16;
  const int sw = (lrow&7)<<4;                     // per-lane read swizzle (bytes)

  // W_hh^T fragments, resident in 64 VGPRs for the whole kernel
  short8 bfrag[16];
  {
    const short* wp = WhhT + (size_t)(w*512 + jbase + lrow)*512 + lhi*8;
    #pragma unroll
    for (int ks=0; ks<16; ++ks)
      bfrag[ks] = *reinterpret_cast<const short8*>(wp + ks*32);
  }
  // static gate part (t-invariant): Gs[b][w*512+jbase+lrow], b per (fm,ri)
  float gsr[16];
  #pragma unroll
  for (int fm=0; fm<4; ++fm)
    #pragma unroll
    for (int ri=0; ri<4; ++ri)
      gsr[fm*4+ri] = Gs[(size_t)(fm*16 + lhi*4 + ri)*2048 + w*512 + jbase + lrow];

  // cell-state registers: thread owns (cb, jbase+cj .. +4)
  const int cb = tid>>2, cj = (tid&3)*4;
  float mreg[4];
  #pragma unroll
  for (int q=0; q<4; ++q) mreg[q] = m0[(size_t)cb*512 + jbase + cj + q];

  for (int t=0; t<NT; ++t) {
    // ---- stage h_t: LDS[B] = hbf[(B&~1023) | ((B&1023)^((row&7)<<4))] ----
    {
      const char* hbytes = (const char*)((t&1) ? hbf1 : hbf0);
      #pragma unroll
      for (int q=0; q<16; ++q) {                   // 16*256*16B = 64KB (all 64 rows)
        const int B = (q*256 + tid)*16;
        const int r = B >> 10;
        const int src = (r<<10) | ((B & 1023) ^ ((r&7)<<4));
        *reinterpret_cast<short8*>(smem + B) =
            *reinterpret_cast<const short8*>(hbytes + src);
      }
    }
    // prefetch this step's embedding gate part
    float ger[16];
    {
      const float* ge = Ge + (size_t)t*NB*2048;
      #pragma unroll
      for (int fm=0; fm<4; ++fm)
        #pragma unroll
        for (int ri=0; ri<4; ++ri)
          ger[fm*4+ri] = ge[(size_t)(fm*16 + lhi*4 + ri)*2048 + w*512 + jbase + lrow];
    }
    __syncthreads();

    // ---- h_t @ W_hh (gate w, 16 cols): 4 m-frags x 16 k-steps ----
    f32x4 acc[4];
    #pragma unroll
    for (int fm=0; fm<4; ++fm){ f32x4 z = {0.f,0.f,0.f,0.f}; acc[fm] = z; }
    #pragma unroll
    for (int ks=0; ks<16; ++ks) {
      const int kb = ks*64 + lhi*16;               // byte offset of lane's k-slice
      #pragma unroll
      for (int fm=0; fm<4; ++fm) {
        const int r = fm*16 + lrow;
        const short8 a = *reinterpret_cast<const short8*>(smem + r*1024 + (kb ^ sw));
        acc[fm] = __builtin_amdgcn_mfma_f32_16x16x32_bf16(
            __builtin_bit_cast(bf16x8, a),
            __builtin_bit_cast(bf16x8, bfrag[ks]), acc[fm], 0, 0, 0);
      }
    }
    __syncthreads();   // all h reads done before gshm (aliased) is written

    // gates -> LDS (MFMA C layout: col=lane&15, row=(lane>>4)*4+reg)
    #pragma unroll
    for (int fm=0; fm<4; ++fm)
      #pragma unroll
      for (int ri=0; ri<4; ++ri)
        gshm[w][fm*16 + lhi*4 + ri][lrow] = acc[fm][ri] + gsr[fm*4+ri] + ger[fm*4+ri];
    __syncthreads();

    // ---- cell update (4 elements/thread, m in registers) ----
    float h2v[4];
    #pragma unroll
    for (int q=0; q<4; ++q) {
      const float gi = gshm[0][cb][cj+q];
      const float gf = gshm[1][cb][cj+q];
      const float gg = gshm[2][cb][cj+q];
      const float go = gshm[3][cb][cj+q];
      mreg[q] = sigm(gf)*mreg[q] + sigm(gi)*tanh_f(gg);
      h2v[q]  = sigm(go)*tanh_f(mreg[q]);
    }
    {
      float* ho = Hout + ((size_t)t*NB + cb)*NH + jbase + cj;
      ho[0]=h2v[0]; ho[1]=h2v[1]; ho[2]=h2v[2]; ho[3]=h2v[3];
      short* hn = ((t&1) ? hbf0 : hbf1) + (size_t)cb*512 + jbase + cj;
      hn[0]=f2bf(h2v[0]); hn[1]=f2bf(h2v[1]); hn[2]=f2bf(h2v[2]); hn[3]=f2bf(h2v[3]);
    }

    // ---- grid barrier (skip after last step) ----
    if (t != NT-1) {
      __syncthreads();                 // drains vmcnt: h stores are in L2
      if (tid == 0) {
        __hip_atomic_fetch_add(ctr, 1u, __ATOMIC_RELEASE, __HIP_MEMORY_SCOPE_AGENT);
        const unsigned tgt = (unsigned)LSTM_BLOCKS * (unsigned)(t+1);
        unsigned spins = 0;
        while (__hip_atomic_load(ctr, __ATOMIC_RELAXED, __HIP_MEMORY_SCOPE_AGENT) < tgt
               && ++spins < (1u<<20)) {
          __builtin_amdgcn_s_sleep(2);
        }
        // one invalidate so subsequent h reads see remote XCDs' writes
        (void)__hip_atomic_load(ctr, __ATOMIC_ACQUIRE, __HIP_MEMORY_SCOPE_AGENT);
      }
      __syncthreads();
    }
  }
}

// ---------------------------------------------------------------------------
// zz[.,196] = dot(tanh(_s+_h), zW)   (one wave per row)
// ---------------------------------------------------------------------------
__global__ __launch_bounds__(256)
void k_zs(const float* __restrict__ Hh, const float* __restrict__ Ss,
          const float* __restrict__ zw, float* __restrict__ zz)
{
  const int wid = blockIdx.x*4 + (threadIdx.x >> 6);   // row (time-major)
  const int l = threadIdx.x & 63;
  const int t = wid >> 6, b = wid & 63;
  float s = 0.f;
  #pragma unroll
  for (int j = 0; j < 8; ++j) {
    const int h = l + 64*j;
    s += tanh_f(Hh[(size_t)wid*NH + h] + Ss[(size_t)wid*NH + h]) * zw[h];
  }
  #pragma unroll
  for (int off = 1; off < 64; off <<= 1) s += __shfl_xor(s, off);
  if (l == 0) zz[((size_t)b*NT + t)*200 + 196] = s;
}

// ---------------------------------------------------------------------------
// zz[b,t,s] = sum_h tanh(v_proj[b,s,h] + _h[b,t,h]) * zW[h]
// block = (s-tile of 16) x one b; v_proj(bf16) read exactly once.
// ---------------------------------------------------------------------------
__global__ __launch_bounds__(256)
void k_att1(const short* __restrict__ vpbf, const float* __restrict__ Hh,
            const float* __restrict__ zw, float* __restrict__ zz)
{
  __shared__ short vp_sh[16][512];
  __shared__ short hh_sh[NT][512];
  __shared__ float zw_sh[512];
  const int b = blockIdx.y, s0 = blockIdx.x*16;
  for (int i = threadIdx.x; i < 1024; i += 256) {        // short8 units
    const int row = i >> 6, c8 = (i & 63)*8;
    const int gs = s0 + row;
    short8 v = {0,0,0,0,0,0,0,0};
    if (gs < NS) v = *reinterpret_cast<const short8*>(&vpbf[((size_t)b*NS + gs)*NH + c8]);
    *reinterpret_cast<short8*>(&vp_sh[row][c8]) = v;
  }
  for (int i = threadIdx.x; i < NT*512; i += 256) {
    const int t = i >> 9, h = i & 511;
    hh_sh[t][h] = f2bf(Hh[((size_t)t*NB + b)*NH + h]);
  }
  for (int i = threadIdx.x; i < 512; i += 256) zw_sh[i] = zw[i];
  __syncthreads();
  const int w = threadIdx.x >> 6, l = threadIdx.x & 63;
  for (int si = w; si < 16; si += 4) {
    const int gs = s0 + si;
    if (gs >= NS) continue;
    float vv[8], zv[8];
    #pragma unroll
    for (int j = 0; j < 8; ++j) {
      const int h = l + 64*j;
      vv[j] = bf2f(vp_sh[si][h]);
      zv[j] = zw_sh[h];
    }
    for (int t = 0; t < NT; ++t) {
      float acc = 0.f;
      #pragma unroll
      for (int j = 0; j < 8; ++j) {
        const int h = l + 64*j;
        acc += tanh_f(vv[j] + bf2f(hh_sh[t][h])) * zv[j];
      }
      #pragma unroll
      for (int off = 1; off < 64; off <<= 1) acc += __shfl_xor(acc, off);
      if (l == 0) zz[((size_t)b*NT + t)*200 + gs] = acc;
    }
  }
}

// ---------------------------------------------------------------------------
// softmax over 197 per row; write masked att to d_out and raw a to ws
// ---------------------------------------------------------------------------
__global__ __launch_bounds__(256)
void k_att2(const float* __restrict__ zz, const int* __restrict__ length,
            float* __restrict__ att, float* __restrict__ abuf)
{
  __shared__ float red[4];
  const int rowm = blockIdx.x;
  const int b = rowm / NT, t = rowm % NT;
  const int tid = threadIdx.x, w = tid >> 6, l = tid & 63;
  float v = -1e30f;
  if (tid < NSP) v = zz[(size_t)rowm*200 + tid];
  float mx = v;
  #pragma unroll
  for (int off = 1; off < 64; off <<= 1) mx = fmaxf(mx, __shfl_xor(mx, off));
  if (l == 0) red[w] = mx;
  __syncthreads();
  mx = fmaxf(fmaxf(red[0], red[1]), fmaxf(red[2], red[3]));
  __syncthreads();
  float p = (tid < NSP) ? __expf(v - mx) : 0.f;
  float sm = p;
  #pragma unroll
  for (int off = 1; off < 64; off <<= 1) sm += __shfl_xor(sm, off);
  if (l == 0) red[w] = sm;
  __syncthreads();
  const float sum = red[0] + red[1] + red[2] + red[3];
  if (tid < NSP) {
    const float a = p / sum;
    abuf[(size_t)rowm*NSP + tid] = a;
    const int msk = (t < length[b] - 1);
    att[(size_t)rowm*NSP + tid] = msk ? a : 0.f;
  }
}

// ---------------------------------------------------------------------------
// c = a[:,:S] @ image + a[:,S]*s ; R = bf16(c + h2)  (per-b, image read ~once)
// ---------------------------------------------------------------------------
__global__ __launch_bounds__(256)
void k_att3(const float* __restrict__ abuf, const float* __restrict__ image,
            const float* __restrict__ HS, const float* __restrict__ H2,
            short* __restrict__ R)
{
  __shared__ float a_sh[NT][NSP];
  const int b = blockIdx.y;
  const int h = blockIdx.x*256 + threadIdx.x;
  for (int i = threadIdx.x; i < NT*NSP; i += 256)
    a_sh[i/NSP][i%NSP] = abuf[((size_t)b*NT + i/NSP)*NSP + (i%NSP)];
  __syncthreads();
  float acc[NT];
  #pragma unroll
  for (int t = 0; t < NT; ++t) acc[t] = 0.f;
  for (int s = 0; s < NS; ++s) {
    const float x = image[((size_t)b*NS + s)*NH + h];
    #pragma unroll
    for (int t = 0; t < NT; ++t) acc[t] = fmaf(a_sh[t][s], x, acc[t]);
  }
  #pragma unroll
  for (int t = 0; t < NT; ++t) {
    const size_t r = (size_t)t*NB + b;            // time-major row
    const float sv  = HS[r*1024 + 512 + h];
    const float h2v = H2[r*NH + h];
    R[((size_t)b*NT + t)*NH + h] = f2bf(acc[t] + a_sh[t][196]*sv + h2v);
  }
}

// ---------------------------------------------------------------------------
// in-place log_softmax(logits)/temp with masking, per row of 10000
// ---------------------------------------------------------------------------
__global__ __launch_bounds__(256)
void k_logsm(float* __restrict__ logp, const int* __restrict__ length,
             const float* __restrict__ temp)
{
  __shared__ float red[4];
  const int row = blockIdx.x;
  const int b = row / NT, t = row % NT;
  float* p = logp + (size_t)row*NV;
  f32x4* p4 = reinterpret_cast<f32x4*>(p);
  const int tid = threadIdx.x, w = tid >> 6, l = tid & 63;
  const bool masked = !(t < length[b] - 1);
  if (masked) {
    f32x4 z = {0.f,0.f,0.f,0.f};
    for (int i = tid; i < NV/4; i += 256) p4[i] = z;
    return;
  }
  float mx = -1e30f;
  for (int i = tid; i < NV/4; i += 256) {
    f32x4 v = p4[i];
    mx = fmaxf(mx, fmaxf(fmaxf(v.x, v.y), fmaxf(v.z, v.w)));
  }
  #pragma unroll
  for (int off = 1; off < 64; off <<= 1) mx = fmaxf(mx, __shfl_xor(mx, off));
  if (l == 0) red[w] = mx;
  __syncthreads();
  mx = fmaxf(fmaxf(red[0], red[1]), fmaxf(red[2], red[3]));
  __syncthreads();
  float sm = 0.f;
  for (int i = tid; i < NV/4; i += 256) {
    f32x4 v = p4[i];
    sm += __expf(v.x - mx) + __expf(v.y - mx) + __expf(v.z - mx) + __expf(v.w - mx);
  }
  #pragma unroll
  for (int off = 1; off < 64; off <<= 1) sm += __shfl_xor(sm, off);
  if (l == 0) red[w] = sm;
  __syncthreads();
  const float lse = __logf(red[0] + red[1] + red[2] + red[3]);
  const float rt = 1.0f / temp[b];
  const float sh = mx + lse;
  for (int i = tid; i < NV/4; i += 256) {
    f32x4 v = p4[i];
    v.x = (v.x - sh)*rt; v.y = (v.y - sh)*rt; v.z = (v.z - sh)*rt; v.w = (v.w - sh)*rt;
    p4[i] = v;
  }
}

// ---------------------------------------------------------------------------
// workspace layout (float units; bf16 buffers count elements/2)
// ---------------------------------------------------------------------------
static const size_t O_STATIC = 0;                              // 64*1048 f32
static const size_t O_IMEAN  = O_STATIC + (size_t)64*1048;
static const size_t O_H0     = O_IMEAN  + (size_t)64*512;
static const size_t O_M      = O_H0     + (size_t)64*512;      // m0 (read-only)
static const size_t O_GSTAT  = O_M      + (size_t)64*512;      // 64*2048 f32
static const size_t O_XEMB   = O_GSTAT  + (size_t)64*2048;     // 1984*512 bf16
static const size_t O_GEMB   = O_XEMB   + (size_t)1984*256;    // 1984*2048 f32
static const size_t O_H2     = O_GEMB   + (size_t)1984*2048;   // 1984*512 f32
static const size_t O_HS     = O_H2     + (size_t)1984*512;    // 1984*1024 f32
static const size_t O_HH     = O_HS     + (size_t)1984*1024;   // 1984*512 f32
static const size_t O_SS     = O_HH     + (size_t)1984*512;    // 1984*512 f32
static const size_t O_R      = O_SS     + (size_t)1984*512;    // 1984*512 bf16
static const size_t O_ZZ     = O_R      + (size_t)1984*256;    // 1984*200 f32
static const size_t O_ABUF   = O_ZZ     + (size_t)1984*200;    // 1984*197 f32
static const size_t O_VPBF   = O_ABUF   + (size_t)1984*197;    // 12544*512 bf16
static const size_t O_WHHT   = O_VPBF   + (size_t)12544*256;   // 2048*512 bf16
static const size_t O_HBF0   = O_WHHT   + (size_t)2048*256;    // 64*512 bf16
static const size_t O_HBF1   = O_HBF0   + (size_t)64*256;
static const size_t O_CTR    = O_HBF1   + (size_t)64*256;      // barrier counter
static const size_t O_WTFCH  = O_CTR    + 64;                  // 512*512 bf16
static const size_t O_WTFCM  = O_WTFCH  + (size_t)512*256;
static const size_t O_WTIHS  = O_WTFCM  + (size_t)512*256;     // 2048*1048 bf16
static const size_t O_WTIHE  = O_WTIHS  + (size_t)2048*524;    // 2048*512 bf16
static const size_t O_WTAV   = O_WTIHE  + (size_t)2048*256;    // 512*512 bf16
static const size_t O_WTAFC  = O_WTAV   + (size_t)512*256;     // 1024*512 bf16
static const size_t O_WTAHH  = O_WTAFC  + (size_t)1024*256;    // 512*512 bf16
static const size_t O_WTASS  = O_WTAHH  + (size_t)512*256;     // 512*512 bf16
static const size_t O_WTFCP  = O_WTASS  + (size_t)512*256;     // 10000*512 bf16
static const size_t OFF_LOGP = (size_t)NB*NT*NSP;              // in d_out floats

extern "C" void kernel_launch(void* const* d_in, const int* in_sizes, int n_in,
                              void* d_out, int out_size, void* d_ws, size_t ws_size,
                              hipStream_t stream) {
  const float* image   = (const float*)d_in[0];
  const float* viewp   = (const float*)d_in[1];
  const float* label   = (const float*)d_in[2];
  const float* topic   = (const float*)d_in[3];
  const float* temp    = (const float*)d_in[4];
  const float* embW    = (const float*)d_in[5];
  const float* fc_h_W  = (const float*)d_in[6];
  const float* fc_h_b  = (const float*)d_in[7];
  const float* fc_m_W  = (const float*)d_in[8];
  const float* fc_m_b  = (const float*)d_in[9];
  const float* W_ih    = (const float*)d_in[10];
  const float* W_hh    = (const float*)d_in[11];
  const float* b_ih    = (const float*)d_in[12];
  const float* b_hh    = (const float*)d_in[13];
  const float* att_fc_W= (const float*)d_in[14];
  const float* att_fc_b= (const float*)d_in[15];
  const float* att_v_W = (const float*)d_in[16];
  const float* att_v_b = (const float*)d_in[17];
  const float* att_hh_W= (const float*)d_in[18];
  const float* att_hh_b= (const float*)d_in[19];
  const float* att_s_W = (const float*)d_in[20];
  const float* att_s_b = (const float*)d_in[21];
  const float* att_z_W = (const float*)d_in[22];
  // d_in[23] att_z_b: constant shift under softmax -> drops out
  const float* fc_p_W  = (const float*)d_in[24];
  const float* fc_p_b  = (const float*)d_in[25];
  const int*   text    = (const int*)d_in[26];
  const int*   length  = (const int*)d_in[27];

  float* ws = (float*)d_ws;
  float* out_att  = (float*)d_out;
  float* out_logp = (float*)d_out + OFF_LOGP;
  short* xemb  = (short*)(ws + O_XEMB);
  short* rbf   = (short*)(ws + O_R);
  short* vpbf  = (short*)(ws + O_VPBF);
  short* whhT  = (short*)(ws + O_WHHT);
  short* hbf0  = (short*)(ws + O_HBF0);
  short* hbf1  = (short*)(ws + O_HBF1);
  unsigned* ctr = (unsigned*)(ws + O_CTR);
  short* wtfch = (short*)(ws + O_WTFCH);
  short* wtfcm = (short*)(ws + O_WTFCM);
  short* wtihs = (short*)(ws + O_WTIHS);
  short* wtihe = (short*)(ws + O_WTIHE);
  short* wtav  = (short*)(ws + O_WTAV);
  short* wtafc = (short*)(ws + O_WTAFC);
  short* wtahh = (short*)(ws + O_WTAHH);
  short* wtass = (short*)(ws + O_WTASS);
  short* wtfcp = (short*)(ws + O_WTFCP);

  // phase 0a: means, gathers, ALL weight transposes in ONE launch
  k_init_ctr<<<1, 64, 0, stream>>>(ctr);
  k_mean_static<<<dim3(2,NB), 256, 0, stream>>>(image, viewp, label, topic,
                                                ws+O_IMEAN, ws+O_STATIC);
  k_gather<<<NB*NT, 256, 0, stream>>>(embW, text, xemb);
  {
    TrJobs jobs;
    auto set = [&](int i, const float* s, short* d, int K, int N){
      jobs.j[i].src = s; jobs.j[i].dst = d; jobs.j[i].K = K; jobs.j[i].N = N;
      jobs.j[i].tcols = (N+31)/32;
    };
    set(0, fc_h_W,  wtfch, 512, 512);
    set(1, fc_m_W,  wtfcm, 512, 512);
    set(2, W_ih,    wtihs, 1048, 2048);
    set(3, W_ih + (size_t)1048*2048, wtihe, 512, 2048);
    set(4, W_hh,    whhT,  512, 2048);
    set(5, att_v_W, wtav,  512, 512);
    set(6, att_fc_W,wtafc, 512, 1024);
    set(7, att_hh_W,wtahh, 512, 512);
    set(8, att_s_W, wtass, 512, 512);
    set(9, fc_p_W,  wtfcp, 512, 10000);
    jobs.cum[0] = 0;
    for (int i = 0; i < NJOBS; ++i) {
      const int trows = (jobs.j[i].K+31)/32;
      jobs.cum[i+1] = jobs.cum[i] + trows*jobs.j[i].tcols;
    }
    k_tr_all<<<jobs.cum[NJOBS], 256, 0, stream>>>(jobs);
  }

  // phase 0b: one-shot GEMMs
  mfma_gemm2<1,0,0><<<dim3(4,1), 256, 0, stream>>>(ws+O_IMEAN,512, wtfch,512,
      fc_h_b,nullptr, ws+O_H0,512, 64,512,512);
  mfma_gemm2<1,0,0><<<dim3(4,1), 256, 0, stream>>>(ws+O_IMEAN,512, wtfcm,512,
      fc_m_b,nullptr, ws+O_M,512, 64,512,512);
  mfma_gemm2<0,0,0><<<dim3(16,1), 256, 0, stream>>>(ws+O_STATIC,1048, wtihs,1048,
      b_ih,b_hh, ws+O_GSTAT,2048, 64,2048,1048);
  mfma_gemm2<0,0,1><<<dim3(16,16), 256, 0, stream>>>(xemb,512, wtihe,512,
      nullptr,nullptr, ws+O_GEMB,2048, 1984,2048,512);
  mfma_gemm2<0,1,0><<<dim3(4,98), 256, 0, stream>>>(image,512, wtav,512,
      att_v_b,nullptr, vpbf,512, 12544,512,512);
  k_f2bf_vec<<<32, 256, 0, stream>>>(ws+O_H0, hbf0, NB*NH);

  // phase 1: whole recurrence in ONE persistent kernel
  lstm_persist<<<LSTM_BLOCKS, 256, 0, stream>>>(ws+O_GSTAT, ws+O_GEMB, whhT,
                                                hbf0, hbf1, ws+O_M, ws+O_H2, ctr);

  // phase 2: batched attention over all B*T rows
  mfma_gemm2<1,0,0><<<dim3(8,16), 256, 0, stream>>>(ws+O_H2,512, wtafc,512,
      att_fc_b,nullptr, ws+O_HS,1024, 1984,1024,512);
  mfma_gemm2<0,0,0><<<dim3(4,16), 256, 0, stream>>>(ws+O_HS,1024, wtahh,512,
      att_hh_b,nullptr, ws+O_HH,512, 1984,512,512);
  mfma_gemm2<0,0,0><<<dim3(4,16), 256, 0, stream>>>(ws+O_HS+512,1024, wtass,512,
      att_s_b,nullptr, ws+O_SS,512, 1984,512,512);
  k_zs<<<NB*NT/4, 256, 0, stream>>>(ws+O_HH, ws+O_SS, att_z_W, ws+O_ZZ);
  k_att1<<<dim3(13,NB), 256, 0, stream>>>(vpbf, ws+O_HH, att_z_W, ws+O_ZZ);
  k_att2<<<NB*NT, 256, 0, stream>>>(ws+O_ZZ, length, out_att, ws+O_ABUF);
  k_att3<<<dim3(2,NB), 256, 0, stream>>>(ws+O_ABUF, image, ws+O_HS, ws+O_H2, rbf);

  // phase 3: vocab projection + fused log_softmax (logits in-place in d_out)
  mfma_gemm2<0,0,1><<<dim3(79,16), 256, 0, stream>>>(rbf,512, wtfcp,512,
      fc_p_b,nullptr, out_logp,10000, 1984,10000,512);
  k_logsm<<<NB*NT, 256, 0, stream>>>(out_logp, length, temp);
}

// Round 8
// 846.235 us; speedup vs baseline: 1.3883x; 1.2383x over previous
//
#include <hip/hip_runtime.h>
#include <hip/hip_bf16.h>

// Problem constants
#define NB 64      // batch
#define NS 196     // image tokens
#define NH 512     // hidden
#define NV 10000   // vocab
#define NL 32      // max length
#define NT 31      // T = L-1
#define NSP 197    // S+1

typedef __attribute__((ext_vector_type(4))) float  f32x4;
typedef __attribute__((ext_vector_type(8))) short  short8;
typedef __attribute__((ext_vector_type(4))) short  s16x4;
typedef __attribute__((ext_vector_type(8))) __bf16 bf16x8;

__device__ __forceinline__ float sigm(float x){ return 1.0f/(1.0f+__expf(-x)); }
__device__ __forceinline__ float tanh_f(float x){ return 1.0f - 2.0f/(1.0f+__expf(2.0f*x)); }
__device__ __forceinline__ short f2bf(float f){
  unsigned u = __float_as_uint(f);
  u += 0x7FFFu + ((u>>16)&1u);           // RNE
  return (short)(u>>16);
}
__device__ __forceinline__ float bf2f(short s){
  return __uint_as_float(((unsigned)(unsigned short)s)<<16);
}

// ---------------------------------------------------------------------------
// Batched transpose+convert: for each job, W (K x N f32) -> Wt (N x K bf16).
// ---------------------------------------------------------------------------
#define NJOBS 10
struct TrJob { const float* src; short* dst; int K; int N; int tcols; };
struct TrJobs { TrJob j[NJOBS]; int cum[NJOBS+1]; };

__global__ __launch_bounds__(256)
void k_tr_all(TrJobs jobs)
{
  __shared__ float tsh[32][33];
  const int g = blockIdx.x;
  int ji = 0;
  #pragma unroll
  for (int i = 0; i < NJOBS; ++i) if (g >= jobs.cum[i+1]) ji = i+1;
  const TrJob J = jobs.j[ji];
  const int lt = g - jobs.cum[ji];
  const int n0 = (lt % J.tcols)*32, k0 = (lt / J.tcols)*32;
  for (int i = threadIdx.x; i < 1024; i += 256) {
    const int kl = i>>5, nl = i&31;
    if (k0+kl < J.K && n0+nl < J.N) tsh[kl][nl] = J.src[(size_t)(k0+kl)*J.N + n0+nl];
  }
  __syncthreads();
  for (int i = threadIdx.x; i < 1024; i += 256) {
    const int nl = i>>5, kl = i&31;
    if (n0+nl < J.N && k0+kl < J.K) J.dst[(size_t)(n0+nl)*J.K + k0+kl] = f2bf(tsh[kl][nl]);
  }
}

// ---------------------------------------------------------------------------
// bf16-MFMA GEMM with pre-transposed B: C = act(A @ B + bias [+ bias2])
// ---------------------------------------------------------------------------
template<int ACT, int CBF, int ABF>
__global__ __launch_bounds__(256)
void mfma_gemm2(const void* __restrict__ Ap, int lda,
                const short* __restrict__ Bt, int ldb,
                const float* __restrict__ bias, const float* __restrict__ bias2,
                void* __restrict__ Cp, int ldc,
                int M, int N, int K)
{
  __shared__ short ash[128][40];
  __shared__ short bsh[128][40];
  const int bn0 = blockIdx.x*128, bm0 = blockIdx.y*128;
  const int tid = threadIdx.x;
  const int w = tid>>6, l = tid&63;
  const int wr = w>>1, wc = w&1;
  const int lrow = l&15, lk = (l>>4)*8;

  f32x4 acc[4][4];
  #pragma unroll
  for (int i=0;i<4;++i)
    #pragma unroll
    for (int j=0;j<4;++j){ f32x4 z = {0.f,0.f,0.f,0.f}; acc[i][j] = z; }

  const int srow = tid>>1, skc = (tid&1)*16;

  const int ksteps = (K+31)>>5;
  for (int ks=0; ks<ksteps; ++ks) {
    const int k0 = ks<<5;
    {
      short8 t0 = {0,0,0,0,0,0,0,0}, t1 = {0,0,0,0,0,0,0,0};
      const int gm = bm0 + srow;
      if (ABF) {
        const short* A = (const short*)Ap;
        if (gm < M) {
          if (k0+skc+16 <= K) {
            const short* src = A + (size_t)gm*lda + (k0+skc);
            t0 = *reinterpret_cast<const short8*>(src);
            t1 = *reinterpret_cast<const short8*>(src+8);
          } else {
            #pragma unroll
            for (int e=0;e<8;++e){ int gk=k0+skc+e;   if (gk<K) t0[e]=A[(size_t)gm*lda+gk]; }
            #pragma unroll
            for (int e=0;e<8;++e){ int gk=k0+skc+8+e; if (gk<K) t1[e]=A[(size_t)gm*lda+gk]; }
          }
        }
      } else {
        const float* A = (const float*)Ap;
        if (gm < M) {
          if (k0+skc+16 <= K) {
            const float* src = A + (size_t)gm*lda + (k0+skc);
            f32x4 v0 = *reinterpret_cast<const f32x4*>(src);
            f32x4 v1 = *reinterpret_cast<const f32x4*>(src+4);
            f32x4 v2 = *reinterpret_cast<const f32x4*>(src+8);
            f32x4 v3 = *reinterpret_cast<const f32x4*>(src+12);
            t0[0]=f2bf(v0.x); t0[1]=f2bf(v0.y); t0[2]=f2bf(v0.z); t0[3]=f2bf(v0.w);
            t0[4]=f2bf(v1.x); t0[5]=f2bf(v1.y); t0[6]=f2bf(v1.z); t0[7]=f2bf(v1.w);
            t1[0]=f2bf(v2.x); t1[1]=f2bf(v2.y); t1[2]=f2bf(v2.z); t1[3]=f2bf(v2.w);
            t1[4]=f2bf(v3.x); t1[5]=f2bf(v3.y); t1[6]=f2bf(v3.z); t1[7]=f2bf(v3.w);
          } else {
            #pragma unroll
            for (int e=0;e<8;++e){ int gk=k0+skc+e;   if (gk<K) t0[e]=f2bf(A[(size_t)gm*lda+gk]); }
            #pragma unroll
            for (int e=0;e<8;++e){ int gk=k0+skc+8+e; if (gk<K) t1[e]=f2bf(A[(size_t)gm*lda+gk]); }
          }
        }
      }
      *reinterpret_cast<short8*>(&ash[srow][skc])   = t0;
      *reinterpret_cast<short8*>(&ash[srow][skc+8]) = t1;
    }
    {
      short8 t0 = {0,0,0,0,0,0,0,0}, t1 = {0,0,0,0,0,0,0,0};
      const int gn = bn0 + srow;
      if (gn < N) {
        if (k0+skc+16 <= K) {
          const short* src = Bt + (size_t)gn*ldb + (k0+skc);
          t0 = *reinterpret_cast<const short8*>(src);
          t1 = *reinterpret_cast<const short8*>(src+8);
        } else {
          #pragma unroll
          for (int e=0;e<8;++e){ int gk=k0+skc+e;   if (gk<K) t0[e]=Bt[(size_t)gn*ldb+gk]; }
          #pragma unroll
          for (int e=0;e<8;++e){ int gk=k0+skc+8+e; if (gk<K) t1[e]=Bt[(size_t)gn*ldb+gk]; }
        }
      }
      *reinterpret_cast<short8*>(&bsh[srow][skc])   = t0;
      *reinterpret_cast<short8*>(&bsh[srow][skc+8]) = t1;
    }
    __syncthreads();
    short8 af[4], bfm[4];
    #pragma unroll
    for (int fm=0;fm<4;++fm) af[fm]  = *reinterpret_cast<const short8*>(&ash[wr*64+fm*16+lrow][lk]);
    #pragma unroll
    for (int fn=0;fn<4;++fn) bfm[fn] = *reinterpret_cast<const short8*>(&bsh[wc*64+fn*16+lrow][lk]);
    #pragma unroll
    for (int fm=0;fm<4;++fm)
      #pragma unroll
      for (int fn=0;fn<4;++fn)
        acc[fm][fn] = __builtin_amdgcn_mfma_f32_16x16x32_bf16(
            __builtin_bit_cast(bf16x8, af[fm]),
            __builtin_bit_cast(bf16x8, bfm[fn]),
            acc[fm][fn], 0, 0, 0);
    __syncthreads();
  }
  #pragma unroll
  for (int fm=0;fm<4;++fm){
    #pragma unroll
    for (int fn=0;fn<4;++fn){
      const int gcol = bn0 + wc*64 + fn*16 + lrow;
      if (gcol >= N) continue;
      float bv = 0.f;
      if (bias)  bv += bias[gcol];
      if (bias2) bv += bias2[gcol];
      const int grow0 = bm0 + wr*64 + fm*16 + (l>>4)*4;
      #pragma unroll
      for (int ri=0;ri<4;++ri){
        const int grow = grow0 + ri;
        if (grow >= M) continue;
        float v = acc[fm][fn][ri] + bv;
        if (ACT==1) v = tanh_f(v);
        if (CBF) reinterpret_cast<short*>(Cp)[(size_t)grow*ldc+gcol] = f2bf(v);
        else     reinterpret_cast<float*>(Cp)[(size_t)grow*ldc+gcol] = v;
      }
    }
  }
}

// ---------------------------------------------------------------------------
// img_mean + static_x assembly.  grid (2, NB) x 256
// ---------------------------------------------------------------------------
__global__ __launch_bounds__(256)
void k_mean_static(const float* __restrict__ image, const float* __restrict__ vp,
                   const float* __restrict__ lab, const float* __restrict__ topic,
                   float* __restrict__ imean, float* __restrict__ statx)
{
  const int b = blockIdx.y;
  const int h = blockIdx.x*256 + threadIdx.x;
  float s = 0.f;
  for (int j = 0; j < NS; ++j) s += image[((size_t)b*NS + j)*NH + h];
  const float mn = s * (1.0f/196.0f);
  imean[b*NH + h]       = mn;
  statx[b*1048 + h]     = mn;
  statx[b*1048 + 536+h] = topic[b*NH + h];
  if (blockIdx.x == 0) {
    if (threadIdx.x < 8)       statx[b*1048 + 512 + threadIdx.x]     = vp[b*8 + threadIdx.x];
    else if (threadIdx.x < 24) statx[b*1048 + 520 + (threadIdx.x-8)] = lab[b*16 + threadIdx.x-8];
  }
}

// ---------------------------------------------------------------------------
// embedding gather -> bf16 (time-major rows r = t*64 + b)
// ---------------------------------------------------------------------------
__global__ __launch_bounds__(256)
void k_gather(const float* __restrict__ embW, const int* __restrict__ text,
              short* __restrict__ X)
{
  const int r = blockIdx.x;
  const int t = r >> 6, b = r & 63;
  const int tok = text[b*NL + t];
  for (int e = threadIdx.x; e < NH; e += 256)
    X[(size_t)r*NH + e] = f2bf(embW[(size_t)tok*NH + e]);
}

// f32 -> bf16 bulk convert (n multiple of 1024)
__global__ __launch_bounds__(256)
void k_f2bf_vec(const float* __restrict__ s, short* __restrict__ d, int n)
{
  int i = (blockIdx.x*256 + threadIdx.x)*4;
  if (i+4 <= n) {
    f32x4 v = *reinterpret_cast<const f32x4*>(s+i);
    s16x4 o; o[0]=f2bf(v.x); o[1]=f2bf(v.y); o[2]=f2bf(v.z); o[3]=f2bf(v.w);
    *reinterpret_cast<s16x4*>(d+i) = o;
  }
}

// zero the 256-u32 flag region (re-poisoned to 0xAA before every launch)
__global__ void k_init_ctr(unsigned* c){ c[threadIdx.x] = 0u; }

// ---------------------------------------------------------------------------
// Persistent LSTM, batch-partitioned: 8 independent GROUPS of 8 batch rows;
// each group = 8 blocks x 512 thr. Block owns 64 gate-cols per gate; wave w
// (of 8): gate w&3, col-half w>>2 (32 cols), weights register-stationary
// (bfrag[2][16] = 128 VGPR). Per step: stage group h (8 rows x 512 bf16, XOR-
// swizzled into LDS rows 0-7; rows 8-15 zeroed once) -> 32 MFMA/wave ->
// gates via LDS -> cell update (m in regs) -> h_{t+1} f32 archive + bf16
// double-buffered -> GROUP barrier: parallel release-STORE to per-block flag
// slot (no RMW serialization; one cacheline per group), wave-parallel
// relaxed 8-flag poll + single acquire. Replaces the 32-participant global
// fetch_add barrier that profiled at 10.4us/step (r5: 323us, MfmaUtil 0.5%).
// ---------------------------------------------------------------------------
__global__ __launch_bounds__(512, 1)
void lstm_persist8(const float* __restrict__ Gs,   // [64][2048]
                   const float* __restrict__ Ge,   // [31][64][2048]
                   const short* __restrict__ WhhT, // [2048][512] bf16
                   short* __restrict__ hbuf0,      // [64][512] bf16 (h_t, t even)
                   short* __restrict__ hbuf1,      // [64][512] bf16 (t odd)
                   const float* __restrict__ m0,   // [64][512]
                   float* __restrict__ Hout,       // [31][64][512] time-major
                   unsigned* __restrict__ flags)   // 8 groups x 32 u32 (128B apart)
{
  __shared__ __align__(16) short hsh[16][512];   // 16KB; rows 8-15 stay zero
  __shared__ float gsh[4][8][68];                // gate exchange
  const int gid = blockIdx.x >> 3, mid = blockIdx.x & 7;
  const int tid = threadIdx.x;
  const int w = tid >> 6, l = tid & 63;
  const int lrow = l & 15, lhi = l >> 4;
  const int gate = w & 3, chalf = w >> 2;
  const int cb = mid*64 + chalf*32;              // wave's col base within gate

  // weight fragments: cols (gate*512 + cb + nf*16 + lrow), k = ks*32+lhi*8
  short8 bfrag[2][16];
  #pragma unroll
  for (int nf=0; nf<2; ++nf) {
    const short* wp = WhhT + (size_t)(gate*512 + cb + nf*16 + lrow)*512 + lhi*8;
    #pragma unroll
    for (int ks=0; ks<16; ++ks)
      bfrag[nf][ks] = *reinterpret_cast<const short8*>(wp + ks*32);
  }

  // cell-update mapping: thread -> (batch row, col)
  const int brow = tid >> 6;              // 0..7
  const int ccol = tid & 63;              // 0..63
  const int gb = gid*8 + brow;            // global batch row
  const int gj = mid*64 + ccol;           // global hidden col
  float mreg = m0[(size_t)gb*NH + gj];
  float gs4[4];
  #pragma unroll
  for (int g=0; g<4; ++g) gs4[g] = Gs[(size_t)gb*2048 + g*512 + gj];

  // zero LDS rows 8-15 once (A-frag padding rows)
  {
    short8 z = {0,0,0,0,0,0,0,0};
    *reinterpret_cast<short8*>((char*)&hsh[0][0] + (8 + (tid>>6))*1024 + (tid&63)*16) = z;
  }

  const int srow = tid >> 6, sc = (tid & 63)*16;   // stage: row, byte col
  const int swS = (srow&7)<<4;
  const unsigned ftgt_base = gid*32;

  for (int t=0; t<NT; ++t) {
    // ---- stage h_t (8 rows x 1KB), XOR-swizzled dest ----
    {
      const char* hb = (const char*)((t&1) ? hbuf1 : hbuf0);
      short8 v = *reinterpret_cast<const short8*>(hb + ((size_t)(gid*8+srow)*512)*2 + sc);
      *reinterpret_cast<short8*>((char*)&hsh[0][0] + srow*1024 + (sc ^ swS)) = v;
    }
    // prefetch this step's embedding gates
    float ge4[4];
    {
      const float* gep = Ge + (size_t)t*NB*2048 + (size_t)gb*2048 + gj;
      #pragma unroll
      for (int g=0; g<4; ++g) ge4[g] = gep[g*512];
    }
    __syncthreads();

    // ---- h @ W_hh slice: 2 nfrags x 16 ksteps ----
    f32x4 acc0 = {0.f,0.f,0.f,0.f}, acc1 = {0.f,0.f,0.f,0.f};
    #pragma unroll
    for (int ks=0; ks<16; ++ks) {
      const int kb = ks*64 + lhi*16;
      const short8 a = *reinterpret_cast<const short8*>(
          (char*)&hsh[0][0] + lrow*1024 + (kb ^ ((lrow&7)<<4)));
      acc0 = __builtin_amdgcn_mfma_f32_16x16x32_bf16(
          __builtin_bit_cast(bf16x8, a), __builtin_bit_cast(bf16x8, bfrag[0][ks]), acc0, 0,0,0);
      acc1 = __builtin_amdgcn_mfma_f32_16x16x32_bf16(
          __builtin_bit_cast(bf16x8, a), __builtin_bit_cast(bf16x8, bfrag[1][ks]), acc1, 0,0,0);
    }
    // gates -> LDS (C layout: col=lane&15, row=(lane>>4)*4+reg; rows 0-7 valid)
    #pragma unroll
    for (int ri=0; ri<4; ++ri) {
      const int row = lhi*4 + ri;
      if (row < 8) {
        gsh[gate][row][chalf*32 + lrow]      = acc0[ri];
        gsh[gate][row][chalf*32 + 16 + lrow] = acc1[ri];
      }
    }
    __syncthreads();

    // ---- cell update (1 element/thread) ----
    const float gi = gsh[0][brow][ccol] + gs4[0] + ge4[0];
    const float gf = gsh[1][brow][ccol] + gs4[1] + ge4[1];
    const float gg = gsh[2][brow][ccol] + gs4[2] + ge4[2];
    const float go = gsh[3][brow][ccol] + gs4[3] + ge4[3];
    mreg = sigm(gf)*mreg + sigm(gi)*tanh_f(gg);
    const float h2 = sigm(go)*tanh_f(mreg);
    Hout[((size_t)t*NB + gb)*NH + gj] = h2;
    *(((t&1) ? hbuf0 : hbuf1) + (size_t)gb*512 + gj) = f2bf(h2);

    // ---- group barrier (8 blocks; skip after last step) ----
    if (t != NT-1) {
      __syncthreads();                 // drains vmcnt: h stores complete
      if (tid == 0)
        __hip_atomic_store(&flags[ftgt_base + mid], (unsigned)(t+1),
                           __ATOMIC_RELEASE, __HIP_MEMORY_SCOPE_AGENT);
      if (tid < 64) {                  // wave 0 polls all 8 flags in parallel
        const unsigned tgt = (unsigned)(t+1);
        unsigned spins = 0;
        for (;;) {
          unsigned f = tgt;
          if (l < 8) f = __hip_atomic_load(&flags[ftgt_base + l],
                                           __ATOMIC_RELAXED, __HIP_MEMORY_SCOPE_AGENT);
          if (__all(f >= tgt) || ++spins >= (1u<<20)) break;
          __builtin_amdgcn_s_sleep(1);
        }
        (void)__hip_atomic_load(&flags[ftgt_base],
                                __ATOMIC_ACQUIRE, __HIP_MEMORY_SCOPE_AGENT);
      }
      __syncthreads();
    }
  }
}

// ---------------------------------------------------------------------------
// zz[.,196] = dot(tanh(_s+_h), zW)   (one wave per row)
// ---------------------------------------------------------------------------
__global__ __launch_bounds__(256)
void k_zs(const float* __restrict__ Hh, const float* __restrict__ Ss,
          const float* __restrict__ zw, float* __restrict__ zz)
{
  const int wid = blockIdx.x*4 + (threadIdx.x >> 6);
  const int l = threadIdx.x & 63;
  const int t = wid >> 6, b = wid & 63;
  float s = 0.f;
  #pragma unroll
  for (int j = 0; j < 8; ++j) {
    const int h = l + 64*j;
    s += tanh_f(Hh[(size_t)wid*NH + h] + Ss[(size_t)wid*NH + h]) * zw[h];
  }
  #pragma unroll
  for (int off = 1; off < 64; off <<= 1) s += __shfl_xor(s, off);
  if (l == 0) zz[((size_t)b*NT + t)*200 + 196] = s;
}

// ---------------------------------------------------------------------------
// zz[b,t,s] = sum_h tanh(v_proj[b,s,h] + _h[b,t,h]) * zW[h]
// ---------------------------------------------------------------------------
__global__ __launch_bounds__(256)
void k_att1(const short* __restrict__ vpbf, const float* __restrict__ Hh,
            const float* __restrict__ zw, float* __restrict__ zz)
{
  __shared__ short vp_sh[16][512];
  __shared__ short hh_sh[NT][512];
  __shared__ float zw_sh[512];
  const int b = blockIdx.y, s0 = blockIdx.x*16;
  for (int i = threadIdx.x; i < 1024; i += 256) {
    const int row = i >> 6, c8 = (i & 63)*8;
    const int gs = s0 + row;
    short8 v = {0,0,0,0,0,0,0,0};
    if (gs < NS) v = *reinterpret_cast<const short8*>(&vpbf[((size_t)b*NS + gs)*NH + c8]);
    *reinterpret_cast<short8*>(&vp_sh[row][c8]) = v;
  }
  for (int i = threadIdx.x; i < NT*512; i += 256) {
    const int t = i >> 9, h = i & 511;
    hh_sh[t][h] = f2bf(Hh[((size_t)t*NB + b)*NH + h]);
  }
  for (int i = threadIdx.x; i < 512; i += 256) zw_sh[i] = zw[i];
  __syncthreads();
  const int w = threadIdx.x >> 6, l = threadIdx.x & 63;
  for (int si = w; si < 16; si += 4) {
    const int gs = s0 + si;
    if (gs >= NS) continue;
    float vv[8], zv[8];
    #pragma unroll
    for (int j = 0; j < 8; ++j) {
      const int h = l + 64*j;
      vv[j] = bf2f(vp_sh[si][h]);
      zv[j] = zw_sh[h];
    }
    for (int t = 0; t < NT; ++t) {
      float acc = 0.f;
      #pragma unroll
      for (int j = 0; j < 8; ++j) {
        const int h = l + 64*j;
        acc += tanh_f(vv[j] + bf2f(hh_sh[t][h])) * zv[j];
      }
      #pragma unroll
      for (int off = 1; off < 64; off <<= 1) acc += __shfl_xor(acc, off);
      if (l == 0) zz[((size_t)b*NT + t)*200 + gs] = acc;
    }
  }
}

// ---------------------------------------------------------------------------
// softmax over 197 per row; write masked att to d_out and raw a to ws
// ---------------------------------------------------------------------------
__global__ __launch_bounds__(256)
void k_att2(const float* __restrict__ zz, const int* __restrict__ length,
            float* __restrict__ att, float* __restrict__ abuf)
{
  __shared__ float red[4];
  const int rowm = blockIdx.x;
  const int b = rowm / NT, t = rowm % NT;
  const int tid = threadIdx.x, w = tid >> 6, l = tid & 63;
  float v = -1e30f;
  if (tid < NSP) v = zz[(size_t)rowm*200 + tid];
  float mx = v;
  #pragma unroll
  for (int off = 1; off < 64; off <<= 1) mx = fmaxf(mx, __shfl_xor(mx, off));
  if (l == 0) red[w] = mx;
  __syncthreads();
  mx = fmaxf(fmaxf(red[0], red[1]), fmaxf(red[2], red[3]));
  __syncthreads();
  float p = (tid < NSP) ? __expf(v - mx) : 0.f;
  float sm = p;
  #pragma unroll
  for (int off = 1; off < 64; off <<= 1) sm += __shfl_xor(sm, off);
  if (l == 0) red[w] = sm;
  __syncthreads();
  const float sum = red[0] + red[1] + red[2] + red[3];
  if (tid < NSP) {
    const float a = p / sum;
    abuf[(size_t)rowm*NSP + tid] = a;
    const int msk = (t < length[b] - 1);
    att[(size_t)rowm*NSP + tid] = msk ? a : 0.f;
  }
}

// ---------------------------------------------------------------------------
// c = a[:,:S] @ image + a[:,S]*s ; R = bf16(c + h2)
// ---------------------------------------------------------------------------
__global__ __launch_bounds__(256)
void k_att3(const float* __restrict__ abuf, const float* __restrict__ image,
            const float* __restrict__ HS, const float* __restrict__ H2,
            short* __restrict__ R)
{
  __shared__ float a_sh[NT][NSP];
  const int b = blockIdx.y;
  const int h = blockIdx.x*256 + threadIdx.x;
  for (int i = threadIdx.x; i < NT*NSP; i += 256)
    a_sh[i/NSP][i%NSP] = abuf[((size_t)b*NT + i/NSP)*NSP + (i%NSP)];
  __syncthreads();
  float acc[NT];
  #pragma unroll
  for (int t = 0; t < NT; ++t) acc[t] = 0.f;
  for (int s = 0; s < NS; ++s) {
    const float x = image[((size_t)b*NS + s)*NH + h];
    #pragma unroll
    for (int t = 0; t < NT; ++t) acc[t] = fmaf(a_sh[t][s], x, acc[t]);
  }
  #pragma unroll
  for (int t = 0; t < NT; ++t) {
    const size_t r = (size_t)t*NB + b;
    const float sv  = HS[r*1024 + 512 + h];
    const float h2v = H2[r*NH + h];
    R[((size_t)b*NT + t)*NH + h] = f2bf(acc[t] + a_sh[t][196]*sv + h2v);
  }
}

// ---------------------------------------------------------------------------
// in-place log_softmax(logits)/temp with masking, per row of 10000
// ---------------------------------------------------------------------------
__global__ __launch_bounds__(256)
void k_logsm(float* __restrict__ logp, const int* __restrict__ length,
             const float* __restrict__ temp)
{
  __shared__ float red[4];
  const int row = blockIdx.x;
  const int b = row / NT, t = row % NT;
  float* p = logp + (size_t)row*NV;
  f32x4* p4 = reinterpret_cast<f32x4*>(p);
  const int tid = threadIdx.x, w = tid >> 6, l = tid & 63;
  const bool masked = !(t < length[b] - 1);
  if (masked) {
    f32x4 z = {0.f,0.f,0.f,0.f};
    for (int i = tid; i < NV/4; i += 256) p4[i] = z;
    return;
  }
  float mx = -1e30f;
  for (int i = tid; i < NV/4; i += 256) {
    f32x4 v = p4[i];
    mx = fmaxf(mx, fmaxf(fmaxf(v.x, v.y), fmaxf(v.z, v.w)));
  }
  #pragma unroll
  for (int off = 1; off < 64; off <<= 1) mx = fmaxf(mx, __shfl_xor(mx, off));
  if (l == 0) red[w] = mx;
  __syncthreads();
  mx = fmaxf(fmaxf(red[0], red[1]), fmaxf(red[2], red[3]));
  __syncthreads();
  float sm = 0.f;
  for (int i = tid; i < NV/4; i += 256) {
    f32x4 v = p4[i];
    sm += __expf(v.x - mx) + __expf(v.y - mx) + __expf(v.z - mx) + __expf(v.w - mx);
  }
  #pragma unroll
  for (int off = 1; off < 64; off <<= 1) sm += __shfl_xor(sm, off);
  if (l == 0) red[w] = sm;
  __syncthreads();
  const float lse = __logf(red[0] + red[1] + red[2] + red[3]);
  const float rt = 1.0f / temp[b];
  const float sh = mx + lse;
  for (int i = tid; i < NV/4; i += 256) {
    f32x4 v = p4[i];
    v.x = (v.x - sh)*rt; v.y = (v.y - sh)*rt; v.z = (v.z - sh)*rt; v.w = (v.w - sh)*rt;
    p4[i] = v;
  }
}

// ---------------------------------------------------------------------------
// workspace layout (float units; bf16 buffers count elements/2)
// ---------------------------------------------------------------------------
static const size_t O_STATIC = 0;                              // 64*1048 f32
static const size_t O_IMEAN  = O_STATIC + (size_t)64*1048;
static const size_t O_H0     = O_IMEAN  + (size_t)64*512;
static const size_t O_M      = O_H0     + (size_t)64*512;      // m0 (read-only)
static const size_t O_GSTAT  = O_M      + (size_t)64*512;      // 64*2048 f32
static const size_t O_XEMB   = O_GSTAT  + (size_t)64*2048;     // 1984*512 bf16
static const size_t O_GEMB   = O_XEMB   + (size_t)1984*256;    // 1984*2048 f32
static const size_t O_H2     = O_GEMB   + (size_t)1984*2048;   // 1984*512 f32
static const size_t O_HS     = O_H2     + (size_t)1984*512;    // 1984*1024 f32
static const size_t O_HH     = O_HS     + (size_t)1984*1024;   // 1984*512 f32
static const size_t O_SS     = O_HH     + (size_t)1984*512;    // 1984*512 f32
static const size_t O_R      = O_SS     + (size_t)1984*512;    // 1984*512 bf16
static const size_t O_ZZ     = O_R      + (size_t)1984*256;    // 1984*200 f32
static const size_t O_ABUF   = O_ZZ     + (size_t)1984*200;    // 1984*197 f32
static const size_t O_VPBF   = O_ABUF   + (size_t)1984*197;    // 12544*512 bf16
static const size_t O_WHHT   = O_VPBF   + (size_t)12544*256;   // 2048*512 bf16
static const size_t O_HBF0   = O_WHHT   + (size_t)2048*256;    // 64*512 bf16
static const size_t O_HBF1   = O_HBF0   + (size_t)64*256;
static const size_t O_CTR    = O_HBF1   + (size_t)64*256;      // 256 u32 flags
static const size_t O_WTFCH  = O_CTR    + 256;                 // 512*512 bf16
static const size_t O_WTFCM  = O_WTFCH  + (size_t)512*256;
static const size_t O_WTIHS  = O_WTFCM  + (size_t)512*256;     // 2048*1048 bf16
static const size_t O_WTIHE  = O_WTIHS  + (size_t)2048*524;    // 2048*512 bf16
static const size_t O_WTAV   = O_WTIHE  + (size_t)2048*256;    // 512*512 bf16
static const size_t O_WTAFC  = O_WTAV   + (size_t)512*256;     // 1024*512 bf16
static const size_t O_WTAHH  = O_WTAFC  + (size_t)1024*256;    // 512*512 bf16
static const size_t O_WTASS  = O_WTAHH  + (size_t)512*256;     // 512*512 bf16
static const size_t O_WTFCP  = O_WTASS  + (size_t)512*256;     // 10000*512 bf16
static const size_t OFF_LOGP = (size_t)NB*NT*NSP;              // in d_out floats

extern "C" void kernel_launch(void* const* d_in, const int* in_sizes, int n_in,
                              void* d_out, int out_size, void* d_ws, size_t ws_size,
                              hipStream_t stream) {
  const float* image   = (const float*)d_in[0];
  const float* viewp   = (const float*)d_in[1];
  const float* label   = (const float*)d_in[2];
  const float* topic   = (const float*)d_in[3];
  const float* temp    = (const float*)d_in[4];
  const float* embW    = (const float*)d_in[5];
  const float* fc_h_W  = (const float*)d_in[6];
  const float* fc_h_b  = (const float*)d_in[7];
  const float* fc_m_W  = (const float*)d_in[8];
  const float* fc_m_b  = (const float*)d_in[9];
  const float* W_ih    = (const float*)d_in[10];
  const float* W_hh    = (const float*)d_in[11];
  const float* b_ih    = (const float*)d_in[12];
  const float* b_hh    = (const float*)d_in[13];
  const float* att_fc_W= (const float*)d_in[14];
  const float* att_fc_b= (const float*)d_in[15];
  const float* att_v_W = (const float*)d_in[16];
  const float* att_v_b = (const float*)d_in[17];
  const float* att_hh_W= (const float*)d_in[18];
  const float* att_hh_b= (const float*)d_in[19];
  const float* att_s_W = (const float*)d_in[20];
  const float* att_s_b = (const float*)d_in[21];
  const float* att_z_W = (const float*)d_in[22];
  // d_in[23] att_z_b: constant shift under softmax -> drops out
  const float* fc_p_W  = (const float*)d_in[24];
  const float* fc_p_b  = (const float*)d_in[25];
  const int*   text    = (const int*)d_in[26];
  const int*   length  = (const int*)d_in[27];

  float* ws = (float*)d_ws;
  float* out_att  = (float*)d_out;
  float* out_logp = (float*)d_out + OFF_LOGP;
  short* xemb  = (short*)(ws + O_XEMB);
  short* rbf   = (short*)(ws + O_R);
  short* vpbf  = (short*)(ws + O_VPBF);
  short* whhT  = (short*)(ws + O_WHHT);
  short* hbf0  = (short*)(ws + O_HBF0);
  short* hbf1  = (short*)(ws + O_HBF1);
  unsigned* ctr = (unsigned*)(ws + O_CTR);
  short* wtfch = (short*)(ws + O_WTFCH);
  short* wtfcm = (short*)(ws + O_WTFCM);
  short* wtihs = (short*)(ws + O_WTIHS);
  short* wtihe = (short*)(ws + O_WTIHE);
  short* wtav  = (short*)(ws + O_WTAV);
  short* wtafc = (short*)(ws + O_WTAFC);
  short* wtahh = (short*)(ws + O_WTAHH);
  short* wtass = (short*)(ws + O_WTASS);
  short* wtfcp = (short*)(ws + O_WTFCP);

  // phase 0a: means, gathers, ALL weight transposes in ONE launch
  k_init_ctr<<<1, 256, 0, stream>>>(ctr);
  k_mean_static<<<dim3(2,NB), 256, 0, stream>>>(image, viewp, label, topic,
                                                ws+O_IMEAN, ws+O_STATIC);
  k_gather<<<NB*NT, 256, 0, stream>>>(embW, text, xemb);
  {
    TrJobs jobs;
    auto set = [&](int i, const float* s, short* d, int K, int N){
      jobs.j[i].src = s; jobs.j[i].dst = d; jobs.j[i].K = K; jobs.j[i].N = N;
      jobs.j[i].tcols = (N+31)/32;
    };
    set(0, fc_h_W,  wtfch, 512, 512);
    set(1, fc_m_W,  wtfcm, 512, 512);
    set(2, W_ih,    wtihs, 1048, 2048);
    set(3, W_ih + (size_t)1048*2048, wtihe, 512, 2048);
    set(4, W_hh,    whhT,  512, 2048);
    set(5, att_v_W, wtav,  512, 512);
    set(6, att_fc_W,wtafc, 512, 1024);
    set(7, att_hh_W,wtahh, 512, 512);
    set(8, att_s_W, wtass, 512, 512);
    set(9, fc_p_W,  wtfcp, 512, 10000);
    jobs.cum[0] = 0;
    for (int i = 0; i < NJOBS; ++i) {
      const int trows = (jobs.j[i].K+31)/32;
      jobs.cum[i+1] = jobs.cum[i] + trows*jobs.j[i].tcols;
    }
    k_tr_all<<<jobs.cum[NJOBS], 256, 0, stream>>>(jobs);
  }

  // phase 0b: one-shot GEMMs
  mfma_gemm2<1,0,0><<<dim3(4,1), 256, 0, stream>>>(ws+O_IMEAN,512, wtfch,512,
      fc_h_b,nullptr, ws+O_H0,512, 64,512,512);
  mfma_gemm2<1,0,0><<<dim3(4,1), 256, 0, stream>>>(ws+O_IMEAN,512, wtfcm,512,
      fc_m_b,nullptr, ws+O_M,512, 64,512,512);
  mfma_gemm2<0,0,0><<<dim3(16,1), 256, 0, stream>>>(ws+O_STATIC,1048, wtihs,1048,
      b_ih,b_hh, ws+O_GSTAT,2048, 64,2048,1048);
  mfma_gemm2<0,0,1><<<dim3(16,16), 256, 0, stream>>>(xemb,512, wtihe,512,
      nullptr,nullptr, ws+O_GEMB,2048, 1984,2048,512);
  mfma_gemm2<0,1,0><<<dim3(4,98), 256, 0, stream>>>(image,512, wtav,512,
      att_v_b,nullptr, vpbf,512, 12544,512,512);
  k_f2bf_vec<<<32, 256, 0, stream>>>(ws+O_H0, hbf0, NB*NH);

  // phase 1: whole recurrence in ONE persistent kernel (8 groups x 8 blocks)
  lstm_persist8<<<64, 512, 0, stream>>>(ws+O_GSTAT, ws+O_GEMB, whhT,
                                        hbf0, hbf1, ws+O_M, ws+O_H2, ctr);

  // phase 2: batched attention over all B*T rows
  mfma_gemm2<1,0,0><<<dim3(8,16), 256, 0, stream>>>(ws+O_H2,512, wtafc,512,
      att_fc_b,nullptr, ws+O_HS,1024, 1984,1024,512);
  mfma_gemm2<0,0,0><<<dim3(4,16), 256, 0, stream>>>(ws+O_HS,1024, wtahh,512,
      att_hh_b,nullptr, ws+O_HH,512, 1984,512,512);
  mfma_gemm2<0,0,0><<<dim3(4,16), 256, 0, stream>>>(ws+O_HS+512,1024, wtass,512,
      att_s_b,nullptr, ws+O_SS,512, 1984,512,512);
  k_zs<<<NB*NT/4, 256, 0, stream>>>(ws+O_HH, ws+O_SS, att_z_W, ws+O_ZZ);
  k_att1<<<dim3(13,NB), 256, 0, stream>>>(vpbf, ws+O_HH, att_z_W, ws+O_ZZ);
  k_att2<<<NB*NT, 256, 0, stream>>>(ws+O_ZZ, length, out_att, ws+O_ABUF);
  k_att3<<<dim3(2,NB), 256, 0, stream>>>(ws+O_ABUF, image, ws+O_HS, ws+O_H2, rbf);

  // phase 3: vocab projection + fused log_softmax (logits in-place in d_out)
  mfma_gemm2<0,0,1><<<dim3(79,16), 256, 0, stream>>>(rbf,512, wtfcp,512,
      fc_p_b,nullptr, out_logp,10000, 1984,10000,512);
  k_logsm<<<NB*NT, 256, 0, stream>>>(out_logp, length, temp);
}